// Round 2
// baseline (915.022 us; speedup 1.0000x reference)
//
#include <hip/hip_runtime.h>

typedef __attribute__((ext_vector_type(8))) short bf16x8;
typedef __attribute__((ext_vector_type(4))) float f32x4;

#define DEVI __device__ __forceinline__

// ---------- helpers ----------

// order-preserving float->uint encoding for atomicMax-based segment max.
// key 0 is reserved as "empty" (below every real encoding incl. -inf).
DEVI unsigned enc_pool(float f) {
  unsigned u = __float_as_uint(f);
  return (u & 0x80000000u) ? ~u : (u | 0x80000000u);
}
DEVI float dec_pool(unsigned k) {
  if (k == 0u) return 0.0f;  // empty voxel -> 0 (matches reference isfinite branch)
  return __uint_as_float((k & 0x80000000u) ? (k ^ 0x80000000u) : ~k);
}
DEVI float eluf(float x) { return x > 0.0f ? x : expm1f(x); }
DEVI unsigned short to_bf16(float f) {  // round-to-nearest-even
  unsigned u = __float_as_uint(f);
  return (unsigned short)((u + 0x7FFFu + ((u >> 16) & 1u)) >> 16);
}

struct Basis { float bw[8]; int kidx[8]; int cell; };

DEVI Basis make_basis(const float* __restrict__ ps, int e) {
  Basis bs;
  float f[3]; int lo[3];
#pragma unroll
  for (int d = 0; d < 3; ++d) {
    float v = ps[e * 3 + d] * 4.0f;                 // pseudo * (K-1)
    float fl = fminf(fmaxf(floorf(v), 0.0f), 3.0f); // clip(floor, 0, K-2)
    lo[d] = (int)fl;
    f[d] = v - fl;
  }
  bs.cell = lo[0] + 4 * lo[1] + 16 * lo[2];
#pragma unroll
  for (int s = 0; s < 8; ++s) {
    int b0 = s & 1, b1 = (s >> 1) & 1, b2 = (s >> 2) & 1;
    bs.bw[s] = (b0 ? f[0] : 1.0f - f[0]) * (b1 ? f[1] : 1.0f - f[1]) *
               (b2 ? f[2] : 1.0f - f[2]);
    bs.kidx[s] = (lo[0] + b0) + 5 * (lo[1] + b1) + 25 * (lo[2] + b2);
  }
  return bs;
}

// ---------- level 1: Cin=1 direct conv ----------
__global__ void sc_conv1(const float* __restrict__ x, const int* __restrict__ ei,
                         const float* __restrict__ ps, const float* __restrict__ W1,
                         float* __restrict__ agg, unsigned* __restrict__ deg) {
  int tid = blockIdx.x * blockDim.x + threadIdx.x;
  int e = tid >> 5, o = tid & 31;
  if (e >= 262144) return;
  int src = ei[e], dst = ei[262144 + e];
  Basis bs = make_basis(ps, e);
  float acc = 0.f;
#pragma unroll
  for (int s = 0; s < 8; ++s) acc += bs.bw[s] * W1[bs.kidx[s] * 32 + o];
  atomicAdd(agg + dst * 32 + o, x[src] * acc);
  if (o == 0) atomicAdd(deg + dst, 1u);
}

// ---------- finalize: h = elu(agg/deg + x@root + b) ----------
template <int CIN, int COUT, bool ENC>
__global__ void sc_finalize(const void* __restrict__ xv, const float* __restrict__ agg,
                            const unsigned* __restrict__ deg, const float* __restrict__ root,
                            const float* __restrict__ bias, float* __restrict__ h, int N) {
  int tid = blockIdx.x * blockDim.x + threadIdx.x;
  if (tid >= N * COUT) return;
  int n = tid / COUT, o = tid % COUT;
  unsigned dv = deg[n];
  float acc = agg[tid] / (float)(dv ? dv : 1u) + bias[o];
#pragma unroll 4
  for (int c = 0; c < CIN; ++c) {
    float xc = ENC ? dec_pool(((const unsigned*)xv)[n * CIN + c])
                   : ((const float*)xv)[n * CIN + c];
    acc += xc * root[c * COUT + o];
  }
  h[tid] = eluf(acc);
}

// ---------- pool: atomicMax of encoded values ----------
template <int COUT>
__global__ void sc_pool(const float* __restrict__ h, const int* __restrict__ cluster,
                        unsigned* __restrict__ out, int N) {
  int tid = blockIdx.x * blockDim.x + threadIdx.x;
  if (tid >= N * COUT) return;
  int n = tid / COUT, o = tid % COUT;
  atomicMax(out + (size_t)cluster[n] * COUT + o, enc_pool(h[tid]));
}

// ---------- binning ----------
__global__ void sc_bin_count(const int* __restrict__ ei, const float* __restrict__ ps,
                             unsigned* __restrict__ count, unsigned* __restrict__ deg, int E) {
  int e = blockIdx.x * blockDim.x + threadIdx.x;
  if (e >= E) return;
  int cell = 0;
#pragma unroll
  for (int d = 0; d < 3; ++d) {
    float v = ps[e * 3 + d] * 4.0f;
    float fl = fminf(fmaxf(floorf(v), 0.0f), 3.0f);
    cell += ((int)fl) << (2 * d);
  }
  atomicAdd(count + cell, 1u);
  atomicAdd(deg + ei[E + e], 1u);
}

__global__ void sc_scan64(const unsigned* __restrict__ count, unsigned* __restrict__ base,
                          unsigned* __restrict__ cursor) {
  int l = threadIdx.x;
  unsigned v = count[l];
  int incl = (int)v;
#pragma unroll
  for (int d = 1; d < 64; d <<= 1) {
    int t = __shfl_up(incl, d);
    if (l >= d) incl += t;
  }
  unsigned excl = (unsigned)incl - v;
  base[l] = excl;
  cursor[l] = excl;
}

// build A matrix rows (cell-sorted): A[pos][s*CIN+c] = bw[s] * x[src][c]  (bf16)
template <int CIN>
__global__ void sc_build_A(const unsigned* __restrict__ xenc, const int* __restrict__ ei,
                           const float* __restrict__ ps, unsigned* __restrict__ cursor,
                           unsigned short* __restrict__ A, int* __restrict__ dsts, int E) {
  int wave = (blockIdx.x * blockDim.x + threadIdx.x) >> 6;
  int lane = threadIdx.x & 63;
  if (wave >= E) return;
  int e = wave;
  int src = ei[e], dst = ei[E + e];
  Basis bs = make_basis(ps, e);
  int p0 = 0;
  if (lane == 0) p0 = (int)atomicAdd(cursor + bs.cell, 1u);
  p0 = __shfl(p0, 0);
  size_t pos = (size_t)p0;
  if (lane == 0) dsts[pos] = dst;
  const int K = 8 * CIN;
  if (CIN == 32) {
    float xs = dec_pool(xenc[src * 32 + (lane & 31)]);
#pragma unroll
    for (int j = 0; j < 4; ++j) {
      int s = j * 2 + (lane >> 5);
      A[pos * K + j * 64 + lane] = to_bf16(bs.bw[s] * xs);
    }
  } else if (CIN == 64) {
    float xs = dec_pool(xenc[src * 64 + lane]);
#pragma unroll
    for (int j = 0; j < 8; ++j)
      A[pos * K + j * 64 + lane] = to_bf16(bs.bw[j] * xs);
  } else {  // CIN == 128
    float xa = dec_pool(xenc[src * 128 + lane]);
    float xb = dec_pool(xenc[src * 128 + 64 + lane]);
#pragma unroll
    for (int j = 0; j < 16; ++j) {
      float xs = (j & 1) ? xb : xa;
      A[pos * K + j * 64 + lane] = to_bf16(bs.bw[j >> 1] * xs);
    }
  }
}

// ---------- W -> bf16 fragment-ready permutation ----------
// Wperm element for matrix k: (c,n) stored at ((kb*COUT + n)*4 + g)*8 + j
// where c = kb*32 + g*8 + j -> B-frag load is one contiguous 16B load per lane.
__global__ void sc_convert_W(const float* __restrict__ W2, const float* __restrict__ W3,
                             const float* __restrict__ W4, unsigned short* __restrict__ P2,
                             unsigned short* __restrict__ P3, unsigned short* __restrict__ P4) {
  int tid = blockIdx.x * blockDim.x + threadIdx.x;
  const int S2 = 125 * 32 * 64, S3 = 125 * 64 * 128, S4 = 125 * 128 * 256;
  const float* W; unsigned short* P; int CIN, COUT, idx;
  if (tid < S2)            { W = W2; P = P2; CIN = 32;  COUT = 64;  idx = tid; }
  else if (tid < S2 + S3)  { W = W3; P = P3; CIN = 64;  COUT = 128; idx = tid - S2; }
  else if (tid < S2 + S3 + S4) { W = W4; P = P4; CIN = 128; COUT = 256; idx = tid - S2 - S3; }
  else return;
  int mat = CIN * COUT;
  int k = idx / mat, off = idx % mat;
  int j = off & 7, g = (off >> 3) & 3;
  int rem = off >> 5;
  int n = rem % COUT, kb = rem / COUT;
  int c = kb * 32 + g * 8 + j;
  P[idx] = to_bf16(W[(k * CIN + c) * COUT + n]);
}

// ---------- per-cell GEMM: C[m,COUT] = A[m,8*CIN] @ Wcell, scatter-add to agg[dst] ----------
template <int CIN, int COUT>
__global__ __launch_bounds__(256) void sc_cell_gemm(
    const unsigned short* __restrict__ A, const unsigned short* __restrict__ Wp,
    const unsigned* __restrict__ base, const unsigned* __restrict__ count,
    const int* __restrict__ dsts, float* __restrict__ agg) {
  constexpr int K = 8 * CIN;
  constexpr int NT = COUT / 16;
  constexpr int KS = K / 32;
  int cell = blockIdx.x;
  int m = (int)count[cell];
  int row0 = blockIdx.y * 64;
  if (row0 >= m) return;
  int cb = (int)base[cell];
  int wv = threadIdx.x >> 6, lane = threadIdx.x & 63;
  int g = lane >> 4, ln = lane & 15;
  int lo0 = cell & 3, lo1 = (cell >> 2) & 3, lo2 = cell >> 4;
  int rrow = row0 + wv * 16 + ln;
  int arow = cb + min(rrow, m - 1);
  f32x4 acc[NT];
#pragma unroll
  for (int t = 0; t < NT; ++t) acc[t] = (f32x4){0.f, 0.f, 0.f, 0.f};
#pragma unroll
  for (int kk = 0; kk < KS; ++kk) {
    int s = (kk * 32) / CIN;
    int kb = ((kk * 32) % CIN) >> 5;
    int b0 = s & 1, b1 = (s >> 1) & 1, b2 = (s >> 2) & 1;
    int ks = (lo0 + b0) + 5 * (lo1 + b1) + 25 * (lo2 + b2);
    bf16x8 af = *(const bf16x8*)(A + (size_t)arow * K + kk * 32 + g * 8);
    const unsigned short* bp = Wp + (size_t)ks * (CIN * COUT);
#pragma unroll
    for (int t = 0; t < NT; ++t) {
      int n = t * 16 + ln;
      bf16x8 bfr = *(const bf16x8*)(bp + (((size_t)kb * COUT + n) * 4 + g) * 8);
      acc[t] = __builtin_amdgcn_mfma_f32_16x16x32_bf16(af, bfr, acc[t], 0, 0, 0);
    }
  }
#pragma unroll
  for (int t = 0; t < NT; ++t) {
#pragma unroll
    for (int r = 0; r < 4; ++r) {
      int row = row0 + wv * 16 + g * 4 + r;  // D layout: row=(lane>>4)*4+r, col=lane&15
      if (row < m) {
        int dst = dsts[cb + row];
        atomicAdd(agg + (size_t)dst * COUT + t * 16 + ln, acc[t][r]);
      }
    }
  }
}

// ---------- FC head ----------
__global__ void sc_fc1(const unsigned* __restrict__ xenc, const float* __restrict__ w,
                       float* __restrict__ out) {
  int j = blockIdx.x * 256 + threadIdx.x;  // 0..511
  int c0 = blockIdx.y * 128;
  float acc[8];
#pragma unroll
  for (int b = 0; b < 8; ++b) acc[b] = 0.f;
  for (int c = c0; c < c0 + 128; ++c) {
    float wv = w[c * 512 + j];
#pragma unroll
    for (int b = 0; b < 8; ++b) acc[b] += dec_pool(xenc[b * 2048 + c]) * wv;
  }
#pragma unroll
  for (int b = 0; b < 8; ++b) atomicAdd(out + b * 512 + j, acc[b]);
}

__global__ void sc_fc2(const float* __restrict__ h, const float* __restrict__ b1,
                       const float* __restrict__ w2, const float* __restrict__ b2,
                       float* __restrict__ out) {
  int b = blockIdx.x;
  int lane = threadIdx.x;  // 64
  float part[10];
#pragma unroll
  for (int o = 0; o < 10; ++o) part[o] = 0.f;
  for (int k = 0; k < 8; ++k) {
    int c = k * 64 + lane;
    float v = eluf(h[b * 512 + c] + b1[c]);
#pragma unroll
    for (int o = 0; o < 10; ++o) part[o] += v * w2[c * 10 + o];
  }
#pragma unroll
  for (int o = 0; o < 10; ++o) {
#pragma unroll
    for (int d = 32; d > 0; d >>= 1) part[o] += __shfl_down(part[o], d);
  }
  if (lane == 0) {
    float z[10], mx = -1e30f;
#pragma unroll
    for (int o = 0; o < 10; ++o) { z[o] = part[o] + b2[o]; mx = fmaxf(mx, z[o]); }
    float sum = 0.f;
#pragma unroll
    for (int o = 0; o < 10; ++o) sum += expf(z[o] - mx);
    float lse = mx + logf(sum);
#pragma unroll
    for (int o = 0; o < 10; ++o) out[b * 10 + o] = z[o] - lse;
  }
}

// ---------- host ----------
extern "C" void kernel_launch(void* const* d_in, const int* in_sizes, int n_in,
                              void* d_out, int out_size, void* d_ws, size_t ws_size,
                              hipStream_t stream) {
  (void)in_sizes; (void)n_in; (void)out_size; (void)ws_size;
  const float* x    = (const float*)d_in[0];
  const int*   ei1  = (const int*)d_in[1];
  const float* ps1  = (const float*)d_in[2];
  const int*   cl1  = (const int*)d_in[3];
  const int*   ei2  = (const int*)d_in[4];
  const float* ps2  = (const float*)d_in[5];
  const int*   cl2  = (const int*)d_in[6];
  const int*   ei3  = (const int*)d_in[7];
  const float* ps3  = (const float*)d_in[8];
  const int*   cl3  = (const int*)d_in[9];
  const int*   ei4  = (const int*)d_in[10];
  const float* ps4  = (const float*)d_in[11];
  const int*   cl4  = (const int*)d_in[12];
  const float* W1   = (const float*)d_in[13];
  const float* root1= (const float*)d_in[14];
  const float* b1   = (const float*)d_in[15];
  const float* W2   = (const float*)d_in[16];
  const float* root2= (const float*)d_in[17];
  const float* b2   = (const float*)d_in[18];
  const float* W3   = (const float*)d_in[19];
  const float* root3= (const float*)d_in[20];
  const float* b3   = (const float*)d_in[21];
  const float* W4   = (const float*)d_in[22];
  const float* root4= (const float*)d_in[23];
  const float* b4   = (const float*)d_in[24];
  const float* fc1w = (const float*)d_in[25];
  const float* fc1b = (const float*)d_in[26];
  const float* fc2w = (const float*)d_in[27];
  const float* fc2b = (const float*)d_in[28];
  float* out = (float*)d_out;

  char* ws = (char*)d_ws;
  size_t off = 0;
  auto alloc = [&](size_t bytes) -> void* {
    void* p = ws + off;
    off = (off + bytes + 255) & ~(size_t)255;
    return p;
  };
  // ---- zero-init region (one memset) ----
  float*    agg1 = (float*)alloc(32768ull * 32 * 4);
  float*    agg2 = (float*)alloc(8192ull * 64 * 4);
  float*    agg3 = (float*)alloc(2048ull * 128 * 4);
  float*    agg4 = (float*)alloc(512ull * 256 * 4);
  unsigned* deg1 = (unsigned*)alloc(32768ull * 4);
  unsigned* deg2 = (unsigned*)alloc(8192ull * 4);
  unsigned* deg3 = (unsigned*)alloc(2048ull * 4);
  unsigned* deg4 = (unsigned*)alloc(512ull * 4);
  unsigned* cnt2 = (unsigned*)alloc(64 * 4);
  unsigned* cnt3 = (unsigned*)alloc(64 * 4);
  unsigned* cnt4 = (unsigned*)alloc(64 * 4);
  unsigned* pe1  = (unsigned*)alloc(8192ull * 32 * 4);
  unsigned* pe2  = (unsigned*)alloc(2048ull * 64 * 4);
  unsigned* pe3  = (unsigned*)alloc(512ull * 128 * 4);
  unsigned* pe4  = (unsigned*)alloc(64ull * 256 * 4);
  float*    fc1o = (float*)alloc(8ull * 512 * 4);
  size_t zero_bytes = off;
  // ---- non-zero region ----
  unsigned* base2 = (unsigned*)alloc(64 * 4);
  unsigned* base3 = (unsigned*)alloc(64 * 4);
  unsigned* base4 = (unsigned*)alloc(64 * 4);
  unsigned* cur2  = (unsigned*)alloc(64 * 4);
  unsigned* cur3  = (unsigned*)alloc(64 * 4);
  unsigned* cur4  = (unsigned*)alloc(64 * 4);
  unsigned short* Wp2 = (unsigned short*)alloc(125ull * 32 * 64 * 2);
  unsigned short* Wp3 = (unsigned short*)alloc(125ull * 64 * 128 * 2);
  unsigned short* Wp4 = (unsigned short*)alloc(125ull * 128 * 256 * 2);
  unsigned short* A   = (unsigned short*)alloc(65536ull * 256 * 2);  // reused L2..L4
  int*            dsts = (int*)alloc(65536ull * 4);                  // reused
  float*          h    = (float*)alloc(32768ull * 32 * 4);           // reused

  hipMemsetAsync(d_ws, 0, zero_bytes, stream);
  sc_convert_W<<<21000, 256, 0, stream>>>(W2, W3, W4, Wp2, Wp3, Wp4);

  // ---- level 1 ----
  sc_conv1<<<32768, 256, 0, stream>>>(x, ei1, ps1, W1, agg1, deg1);
  sc_finalize<1, 32, false><<<4096, 256, 0, stream>>>(x, agg1, deg1, root1, b1, h, 32768);
  sc_pool<32><<<4096, 256, 0, stream>>>(h, cl1, pe1, 32768);

  // ---- level 2 ----
  sc_bin_count<<<256, 256, 0, stream>>>(ei2, ps2, cnt2, deg2, 65536);
  sc_scan64<<<1, 64, 0, stream>>>(cnt2, base2, cur2);
  sc_build_A<32><<<16384, 256, 0, stream>>>(pe1, ei2, ps2, cur2, A, dsts, 65536);
  sc_cell_gemm<32, 64><<<dim3(64, 34), 256, 0, stream>>>(A, Wp2, base2, cnt2, dsts, agg2);
  sc_finalize<32, 64, true><<<2048, 256, 0, stream>>>(pe1, agg2, deg2, root2, b2, h, 8192);
  sc_pool<64><<<2048, 256, 0, stream>>>(h, cl2, pe2, 8192);

  // ---- level 3 ----
  sc_bin_count<<<64, 256, 0, stream>>>(ei3, ps3, cnt3, deg3, 16384);
  sc_scan64<<<1, 64, 0, stream>>>(cnt3, base3, cur3);
  sc_build_A<64><<<4096, 256, 0, stream>>>(pe2, ei3, ps3, cur3, A, dsts, 16384);
  sc_cell_gemm<64, 128><<<dim3(64, 10), 256, 0, stream>>>(A, Wp3, base3, cnt3, dsts, agg3);
  sc_finalize<64, 128, true><<<1024, 256, 0, stream>>>(pe2, agg3, deg3, root3, b3, h, 2048);
  sc_pool<128><<<1024, 256, 0, stream>>>(h, cl3, pe3, 2048);

  // ---- level 4 ----
  sc_bin_count<<<16, 256, 0, stream>>>(ei4, ps4, cnt4, deg4, 4096);
  sc_scan64<<<1, 64, 0, stream>>>(cnt4, base4, cur4);
  sc_build_A<128><<<1024, 256, 0, stream>>>(pe3, ei4, ps4, cur4, A, dsts, 4096);
  sc_cell_gemm<128, 256><<<dim3(64, 4), 256, 0, stream>>>(A, Wp4, base4, cnt4, dsts, agg4);
  sc_finalize<128, 256, true><<<512, 256, 0, stream>>>(pe3, agg4, deg4, root4, b4, h, 512);
  sc_pool<256><<<512, 256, 0, stream>>>(h, cl4, pe4, 512);

  // ---- FC head ----
  sc_fc1<<<dim3(2, 16), 256, 0, stream>>>(pe4, fc1w, fc1o);
  sc_fc2<<<8, 64, 0, stream>>>(fc1o, fc1b, fc2w, fc2b, out);
}

// Round 3
// 564.944 us; speedup vs baseline: 1.6197x; 1.6197x over previous
//
#include <hip/hip_runtime.h>

typedef __attribute__((ext_vector_type(8))) short bf16x8;
typedef __attribute__((ext_vector_type(4))) float f32x4;
typedef __attribute__((ext_vector_type(4))) unsigned short us4;
typedef __attribute__((ext_vector_type(8))) unsigned short us8;

#define DEVI __device__ __forceinline__

// ---------- helpers ----------

DEVI unsigned enc_pool(float f) {
  unsigned u = __float_as_uint(f);
  return (u & 0x80000000u) ? ~u : (u | 0x80000000u);
}
DEVI float dec_pool(unsigned k) {
  if (k == 0u) return 0.0f;  // empty voxel -> 0
  return __uint_as_float((k & 0x80000000u) ? (k ^ 0x80000000u) : ~k);
}
DEVI float eluf(float x) { return x > 0.0f ? x : expm1f(x); }
DEVI unsigned short to_bf16(float f) {  // round-to-nearest-even
  unsigned u = __float_as_uint(f);
  return (unsigned short)((u + 0x7FFFu + ((u >> 16) & 1u)) >> 16);
}

struct Basis { float bw[8]; int kidx[8]; int cell; };

DEVI Basis make_basis(const float* __restrict__ ps, int e) {
  Basis bs;
  float f[3]; int lo[3];
#pragma unroll
  for (int d = 0; d < 3; ++d) {
    float v = ps[e * 3 + d] * 4.0f;
    float fl = fminf(fmaxf(floorf(v), 0.0f), 3.0f);
    lo[d] = (int)fl;
    f[d] = v - fl;
  }
  bs.cell = lo[0] + 4 * lo[1] + 16 * lo[2];
#pragma unroll
  for (int s = 0; s < 8; ++s) {
    int b0 = s & 1, b1 = (s >> 1) & 1, b2 = (s >> 2) & 1;
    bs.bw[s] = (b0 ? f[0] : 1.0f - f[0]) * (b1 ? f[1] : 1.0f - f[1]) *
               (b2 ? f[2] : 1.0f - f[2]);
    bs.kidx[s] = (lo[0] + b0) + 5 * (lo[1] + b1) + 25 * (lo[2] + b2);
  }
  return bs;
}

// ---------- level 1: Cin=1 direct conv ----------
__global__ void sc_conv1(const float* __restrict__ x, const int* __restrict__ ei,
                         const float* __restrict__ ps, const float* __restrict__ W1,
                         float* __restrict__ agg, unsigned* __restrict__ deg) {
  int tid = blockIdx.x * blockDim.x + threadIdx.x;
  int e = tid >> 5, o = tid & 31;
  if (e >= 262144) return;
  int src = ei[e], dst = ei[262144 + e];
  Basis bs = make_basis(ps, e);
  float acc = 0.f;
#pragma unroll
  for (int s = 0; s < 8; ++s) acc += bs.bw[s] * W1[bs.kidx[s] * 32 + o];
  atomicAdd(agg + dst * 32 + o, x[src] * acc);
  if (o == 0) atomicAdd(deg + dst, 1u);
}

// ---------- finalize: h = elu(agg/deg + x@root + b) ----------
template <int CIN, int COUT, bool ENC>
__global__ void sc_finalize(const void* __restrict__ xv, const float* __restrict__ agg,
                            const unsigned* __restrict__ deg, const float* __restrict__ root,
                            const float* __restrict__ bias, float* __restrict__ h, int N) {
  int tid = blockIdx.x * blockDim.x + threadIdx.x;
  if (tid >= N * COUT) return;
  int n = tid / COUT, o = tid % COUT;
  unsigned dv = deg[n];
  float acc = agg[tid] / (float)(dv ? dv : 1u) + bias[o];
#pragma unroll 4
  for (int c = 0; c < CIN; ++c) {
    float xc = ENC ? dec_pool(((const unsigned*)xv)[n * CIN + c])
                   : ((const float*)xv)[n * CIN + c];
    acc += xc * root[c * COUT + o];
  }
  h[tid] = eluf(acc);
}

// ---------- pool: atomicMax of encoded values ----------
template <int COUT>
__global__ void sc_pool(const float* __restrict__ h, const int* __restrict__ cluster,
                        unsigned* __restrict__ out, int N) {
  int tid = blockIdx.x * blockDim.x + threadIdx.x;
  if (tid >= N * COUT) return;
  int n = tid / COUT, o = tid % COUT;
  atomicMax(out + (size_t)cluster[n] * COUT + o, enc_pool(h[tid]));
}

// ---------- counting: per-block 64-cell histogram, zero global atomics on cells ----------
// grid: 64 (L2) + 16 (L3) + 4 (L4) blocks x 1024 threads, 1024 edges/block.
__global__ __launch_bounds__(1024) void sc_count_all(
    const int* __restrict__ ei2, const float* __restrict__ ps2,
    const int* __restrict__ ei3, const float* __restrict__ ps3,
    const int* __restrict__ ei4, const float* __restrict__ ps4,
    unsigned* __restrict__ bc2, unsigned* __restrict__ bc3, unsigned* __restrict__ bc4,
    unsigned* __restrict__ deg2, unsigned* __restrict__ deg3, unsigned* __restrict__ deg4) {
  __shared__ unsigned hist[64];
  int b = blockIdx.x, t = threadIdx.x;
  const int* ei; const float* ps; unsigned *bc, *deg; int E, blk, NB;
  if (b < 64)      { ei = ei2; ps = ps2; bc = bc2; deg = deg2; E = 65536; blk = b;      NB = 64; }
  else if (b < 80) { ei = ei3; ps = ps3; bc = bc3; deg = deg3; E = 16384; blk = b - 64; NB = 16; }
  else             { ei = ei4; ps = ps4; bc = bc4; deg = deg4; E = 4096;  blk = b - 80; NB = 4;  }
  if (t < 64) hist[t] = 0;
  __syncthreads();
  int e = blk * 1024 + t;
  int cell = 0;
#pragma unroll
  for (int d = 0; d < 3; ++d) {
    float v = ps[e * 3 + d] * 4.0f;
    float fl = fminf(fmaxf(floorf(v), 0.0f), 3.0f);
    cell |= ((int)fl) << (2 * d);
  }
  atomicAdd(&hist[cell], 1u);           // LDS atomic
  atomicAdd(deg + ei[E + e], 1u);       // spread over N addresses
  __syncthreads();
  if (t < 64) bc[(size_t)t * NB + blk] = hist[t];
}

// ---------- scan: per-(cell,block) bases + per-cell totals, one tiny block ----------
// wave w handles level w+2 entirely (serial over 64 cells, lane-parallel over blocks).
__global__ void sc_scan_all(const unsigned* __restrict__ bc2, const unsigned* __restrict__ bc3,
                            const unsigned* __restrict__ bc4,
                            unsigned* __restrict__ bb2, unsigned* __restrict__ bb3,
                            unsigned* __restrict__ bb4,
                            unsigned* __restrict__ cnt2, unsigned* __restrict__ cnt3,
                            unsigned* __restrict__ cnt4,
                            unsigned* __restrict__ base2, unsigned* __restrict__ base3,
                            unsigned* __restrict__ base4) {
  int w = threadIdx.x >> 6, lane = threadIdx.x & 63;
  const unsigned* bc; unsigned *bb, *cnt, *bs; int NB;
  if (w == 0)      { bc = bc2; bb = bb2; cnt = cnt2; bs = base2; NB = 64; }
  else if (w == 1) { bc = bc3; bb = bb3; cnt = cnt3; bs = base3; NB = 16; }
  else if (w == 2) { bc = bc4; bb = bb4; cnt = cnt4; bs = base4; NB = 4;  }
  else return;
  unsigned run = 0;
  for (int c = 0; c < 64; ++c) {
    unsigned v = (lane < NB) ? bc[c * NB + lane] : 0u;
    int incl = (int)v;
#pragma unroll
    for (int d = 1; d < 64; d <<= 1) {
      int tv = __shfl_up(incl, d);
      if (lane >= d) incl += tv;
    }
    unsigned tot = (unsigned)__shfl(incl, NB - 1);
    if (lane < NB) bb[c * NB + lane] = run + (unsigned)incl - v;
    if (lane == 0) { cnt[c] = tot; bs[c] = run; }
    run += tot;
  }
}

// ---------- build A rows (cell-sorted), atomic-free positions ----------
// A[pos][idx] = bw[idx / CIN] * x[src][idx % CIN]   (bf16), K = 8*CIN
// phase B identity: for lane covering idx = lane*(K/64)+q -> s = lane>>3 for all CIN.
template <int CIN>
__global__ __launch_bounds__(1024) void sc_build_A(
    const unsigned* __restrict__ xenc, const int* __restrict__ ei,
    const float* __restrict__ ps, const unsigned* __restrict__ blkbase, int NB,
    unsigned short* __restrict__ A, int* __restrict__ dsts, int E) {
  __shared__ unsigned hist[64];
  __shared__ int s_src[1024];
  __shared__ int s_pos[1024];
  __shared__ float s_bw[8][1025];
  int t = threadIdx.x, blk = blockIdx.x;
  if (t < 64) hist[t] = 0;
  __syncthreads();
  int e = blk * 1024 + t;
  int src = ei[e], dst = ei[E + e];
  Basis bs = make_basis(ps, e);
  unsigned r = atomicAdd(&hist[bs.cell], 1u);  // LDS rank within (block, cell)
  int pos = (int)(blkbase[bs.cell * NB + blk] + r);
  s_src[t] = src;
  s_pos[t] = pos;
#pragma unroll
  for (int s = 0; s < 8; ++s) s_bw[s][t] = bs.bw[s];
  dsts[pos] = dst;
  __syncthreads();
  int wv = t >> 6, lane = t & 63;
  int sB = lane >> 3;
  constexpr int K = 8 * CIN;
  for (int el = wv; el < 1024; el += 16) {
    int p = s_pos[el], sr = s_src[el];
    float b = s_bw[sB][el];
    if (CIN == 32) {
      uint4 xv = *(const uint4*)(xenc + (size_t)sr * 32 + (lane & 7) * 4);
      us4 o;
      o[0] = to_bf16(b * dec_pool(xv.x)); o[1] = to_bf16(b * dec_pool(xv.y));
      o[2] = to_bf16(b * dec_pool(xv.z)); o[3] = to_bf16(b * dec_pool(xv.w));
      *(us4*)(A + (size_t)p * K + lane * 4) = o;
    } else if (CIN == 64) {
      const uint4* xp = (const uint4*)(xenc + (size_t)sr * 64 + (lane & 7) * 8);
      uint4 xa = xp[0], xb = xp[1];
      us8 o;
      o[0] = to_bf16(b * dec_pool(xa.x)); o[1] = to_bf16(b * dec_pool(xa.y));
      o[2] = to_bf16(b * dec_pool(xa.z)); o[3] = to_bf16(b * dec_pool(xa.w));
      o[4] = to_bf16(b * dec_pool(xb.x)); o[5] = to_bf16(b * dec_pool(xb.y));
      o[6] = to_bf16(b * dec_pool(xb.z)); o[7] = to_bf16(b * dec_pool(xb.w));
      *(us8*)(A + (size_t)p * K + lane * 8) = o;
    } else {  // CIN == 128
      const uint4* xp = (const uint4*)(xenc + (size_t)sr * 128 + (lane & 7) * 16);
#pragma unroll
      for (int h = 0; h < 2; ++h) {
        uint4 xa = xp[h * 2], xb = xp[h * 2 + 1];
        us8 o;
        o[0] = to_bf16(b * dec_pool(xa.x)); o[1] = to_bf16(b * dec_pool(xa.y));
        o[2] = to_bf16(b * dec_pool(xa.z)); o[3] = to_bf16(b * dec_pool(xa.w));
        o[4] = to_bf16(b * dec_pool(xb.x)); o[5] = to_bf16(b * dec_pool(xb.y));
        o[6] = to_bf16(b * dec_pool(xb.z)); o[7] = to_bf16(b * dec_pool(xb.w));
        *(us8*)(A + (size_t)p * K + lane * 16 + h * 8) = o;
      }
    }
  }
}

// ---------- W -> bf16 fragment-ready permutation ----------
__global__ void sc_convert_W(const float* __restrict__ W2, const float* __restrict__ W3,
                             const float* __restrict__ W4, unsigned short* __restrict__ P2,
                             unsigned short* __restrict__ P3, unsigned short* __restrict__ P4) {
  int tid = blockIdx.x * blockDim.x + threadIdx.x;
  const int S2 = 125 * 32 * 64, S3 = 125 * 64 * 128, S4 = 125 * 128 * 256;
  const float* W; unsigned short* P; int CIN, COUT, idx;
  if (tid < S2)            { W = W2; P = P2; CIN = 32;  COUT = 64;  idx = tid; }
  else if (tid < S2 + S3)  { W = W3; P = P3; CIN = 64;  COUT = 128; idx = tid - S2; }
  else if (tid < S2 + S3 + S4) { W = W4; P = P4; CIN = 128; COUT = 256; idx = tid - S2 - S3; }
  else return;
  int mat = CIN * COUT;
  int k = idx / mat, off = idx % mat;
  int j = off & 7, g = (off >> 3) & 3;
  int rem = off >> 5;
  int n = rem % COUT, kb = rem / COUT;
  int c = kb * 32 + g * 8 + j;
  P[idx] = to_bf16(W[(k * CIN + c) * COUT + n]);
}

// ---------- per-cell GEMM: C[m,COUT] = A[m,8*CIN] @ Wcell, scatter-add to agg[dst] ----------
template <int CIN, int COUT>
__global__ __launch_bounds__(256) void sc_cell_gemm(
    const unsigned short* __restrict__ A, const unsigned short* __restrict__ Wp,
    const unsigned* __restrict__ base, const unsigned* __restrict__ count,
    const int* __restrict__ dsts, float* __restrict__ agg) {
  constexpr int K = 8 * CIN;
  constexpr int NT = COUT / 16;
  constexpr int KS = K / 32;
  int cell = blockIdx.x;
  int m = (int)count[cell];
  int row0 = blockIdx.y * 64;
  if (row0 >= m) return;
  int cb = (int)base[cell];
  int wv = threadIdx.x >> 6, lane = threadIdx.x & 63;
  int g = lane >> 4, ln = lane & 15;
  int lo0 = cell & 3, lo1 = (cell >> 2) & 3, lo2 = cell >> 4;
  int rrow = row0 + wv * 16 + ln;
  int arow = cb + min(rrow, m - 1);
  f32x4 acc[NT];
#pragma unroll
  for (int t = 0; t < NT; ++t) acc[t] = (f32x4){0.f, 0.f, 0.f, 0.f};
#pragma unroll
  for (int kk = 0; kk < KS; ++kk) {
    int s = (kk * 32) / CIN;
    int kb = ((kk * 32) % CIN) >> 5;
    int b0 = s & 1, b1 = (s >> 1) & 1, b2 = (s >> 2) & 1;
    int ks = (lo0 + b0) + 5 * (lo1 + b1) + 25 * (lo2 + b2);
    bf16x8 af = *(const bf16x8*)(A + (size_t)arow * K + kk * 32 + g * 8);
    const unsigned short* bp = Wp + (size_t)ks * (CIN * COUT);
#pragma unroll
    for (int t = 0; t < NT; ++t) {
      int n = t * 16 + ln;
      bf16x8 bfr = *(const bf16x8*)(bp + (((size_t)kb * COUT + n) * 4 + g) * 8);
      acc[t] = __builtin_amdgcn_mfma_f32_16x16x32_bf16(af, bfr, acc[t], 0, 0, 0);
    }
  }
#pragma unroll
  for (int t = 0; t < NT; ++t) {
#pragma unroll
    for (int r = 0; r < 4; ++r) {
      int row = row0 + wv * 16 + g * 4 + r;  // D: row=(lane>>4)*4+r, col=lane&15
      if (row < m) {
        int dst = dsts[cb + row];
        atomicAdd(agg + (size_t)dst * COUT + t * 16 + ln, acc[t][r]);
      }
    }
  }
}

// ---------- FC head ----------
__global__ void sc_fc1(const unsigned* __restrict__ xenc, const float* __restrict__ w,
                       float* __restrict__ out) {
  int j = blockIdx.x * 256 + threadIdx.x;
  int c0 = blockIdx.y * 128;
  float acc[8];
#pragma unroll
  for (int b = 0; b < 8; ++b) acc[b] = 0.f;
  for (int c = c0; c < c0 + 128; ++c) {
    float wv = w[c * 512 + j];
#pragma unroll
    for (int b = 0; b < 8; ++b) acc[b] += dec_pool(xenc[b * 2048 + c]) * wv;
  }
#pragma unroll
  for (int b = 0; b < 8; ++b) atomicAdd(out + b * 512 + j, acc[b]);
}

__global__ void sc_fc2(const float* __restrict__ h, const float* __restrict__ b1,
                       const float* __restrict__ w2, const float* __restrict__ b2,
                       float* __restrict__ out) {
  int b = blockIdx.x;
  int lane = threadIdx.x;
  float part[10];
#pragma unroll
  for (int o = 0; o < 10; ++o) part[o] = 0.f;
  for (int k = 0; k < 8; ++k) {
    int c = k * 64 + lane;
    float v = eluf(h[b * 512 + c] + b1[c]);
#pragma unroll
    for (int o = 0; o < 10; ++o) part[o] += v * w2[c * 10 + o];
  }
#pragma unroll
  for (int o = 0; o < 10; ++o) {
#pragma unroll
    for (int d = 32; d > 0; d >>= 1) part[o] += __shfl_down(part[o], d);
  }
  if (lane == 0) {
    float z[10], mx = -1e30f;
#pragma unroll
    for (int o = 0; o < 10; ++o) { z[o] = part[o] + b2[o]; mx = fmaxf(mx, z[o]); }
    float sum = 0.f;
#pragma unroll
    for (int o = 0; o < 10; ++o) sum += expf(z[o] - mx);
    float lse = mx + logf(sum);
#pragma unroll
    for (int o = 0; o < 10; ++o) out[b * 10 + o] = z[o] - lse;
  }
}

// ---------- host ----------
extern "C" void kernel_launch(void* const* d_in, const int* in_sizes, int n_in,
                              void* d_out, int out_size, void* d_ws, size_t ws_size,
                              hipStream_t stream) {
  (void)in_sizes; (void)n_in; (void)out_size; (void)ws_size;
  const float* x    = (const float*)d_in[0];
  const int*   ei1  = (const int*)d_in[1];
  const float* ps1  = (const float*)d_in[2];
  const int*   cl1  = (const int*)d_in[3];
  const int*   ei2  = (const int*)d_in[4];
  const float* ps2  = (const float*)d_in[5];
  const int*   cl2  = (const int*)d_in[6];
  const int*   ei3  = (const int*)d_in[7];
  const float* ps3  = (const float*)d_in[8];
  const int*   cl3  = (const int*)d_in[9];
  const int*   ei4  = (const int*)d_in[10];
  const float* ps4  = (const float*)d_in[11];
  const int*   cl4  = (const int*)d_in[12];
  const float* W1   = (const float*)d_in[13];
  const float* root1= (const float*)d_in[14];
  const float* b1   = (const float*)d_in[15];
  const float* W2   = (const float*)d_in[16];
  const float* root2= (const float*)d_in[17];
  const float* b2   = (const float*)d_in[18];
  const float* W3   = (const float*)d_in[19];
  const float* root3= (const float*)d_in[20];
  const float* b3   = (const float*)d_in[21];
  const float* W4   = (const float*)d_in[22];
  const float* root4= (const float*)d_in[23];
  const float* b4   = (const float*)d_in[24];
  const float* fc1w = (const float*)d_in[25];
  const float* fc1b = (const float*)d_in[26];
  const float* fc2w = (const float*)d_in[27];
  const float* fc2b = (const float*)d_in[28];
  float* out = (float*)d_out;

  char* ws = (char*)d_ws;
  size_t off = 0;
  auto alloc = [&](size_t bytes) -> void* {
    void* p = ws + off;
    off = (off + bytes + 255) & ~(size_t)255;
    return p;
  };
  // ---- zero-init region (one memset) ----
  float*    agg1 = (float*)alloc(32768ull * 32 * 4);
  float*    agg2 = (float*)alloc(8192ull * 64 * 4);
  float*    agg3 = (float*)alloc(2048ull * 128 * 4);
  float*    agg4 = (float*)alloc(512ull * 256 * 4);
  unsigned* deg1 = (unsigned*)alloc(32768ull * 4);
  unsigned* deg2 = (unsigned*)alloc(8192ull * 4);
  unsigned* deg3 = (unsigned*)alloc(2048ull * 4);
  unsigned* deg4 = (unsigned*)alloc(512ull * 4);
  unsigned* pe1  = (unsigned*)alloc(8192ull * 32 * 4);
  unsigned* pe2  = (unsigned*)alloc(2048ull * 64 * 4);
  unsigned* pe3  = (unsigned*)alloc(512ull * 128 * 4);
  unsigned* pe4  = (unsigned*)alloc(64ull * 256 * 4);
  float*    fc1o = (float*)alloc(8ull * 512 * 4);
  size_t zero_bytes = off;
  // ---- non-zero region (fully written each call) ----
  unsigned* bc2   = (unsigned*)alloc(64ull * 64 * 4);
  unsigned* bc3   = (unsigned*)alloc(64ull * 16 * 4);
  unsigned* bc4   = (unsigned*)alloc(64ull * 4 * 4);
  unsigned* bb2   = (unsigned*)alloc(64ull * 64 * 4);
  unsigned* bb3   = (unsigned*)alloc(64ull * 16 * 4);
  unsigned* bb4   = (unsigned*)alloc(64ull * 4 * 4);
  unsigned* cnt2  = (unsigned*)alloc(64 * 4);
  unsigned* cnt3  = (unsigned*)alloc(64 * 4);
  unsigned* cnt4  = (unsigned*)alloc(64 * 4);
  unsigned* base2 = (unsigned*)alloc(64 * 4);
  unsigned* base3 = (unsigned*)alloc(64 * 4);
  unsigned* base4 = (unsigned*)alloc(64 * 4);
  unsigned short* Wp2 = (unsigned short*)alloc(125ull * 32 * 64 * 2);
  unsigned short* Wp3 = (unsigned short*)alloc(125ull * 64 * 128 * 2);
  unsigned short* Wp4 = (unsigned short*)alloc(125ull * 128 * 256 * 2);
  unsigned short* A   = (unsigned short*)alloc(65536ull * 256 * 2);  // reused L2..L4
  int*            dsts = (int*)alloc(65536ull * 4);                  // reused
  float*          h    = (float*)alloc(32768ull * 32 * 4);           // reused

  hipMemsetAsync(d_ws, 0, zero_bytes, stream);
  sc_convert_W<<<21000, 256, 0, stream>>>(W2, W3, W4, Wp2, Wp3, Wp4);
  // counting + scans for all levels depend only on inputs -> run up front
  sc_count_all<<<84, 1024, 0, stream>>>(ei2, ps2, ei3, ps3, ei4, ps4,
                                        bc2, bc3, bc4, deg2, deg3, deg4);
  sc_scan_all<<<1, 256, 0, stream>>>(bc2, bc3, bc4, bb2, bb3, bb4,
                                     cnt2, cnt3, cnt4, base2, base3, base4);

  // ---- level 1 ----
  sc_conv1<<<32768, 256, 0, stream>>>(x, ei1, ps1, W1, agg1, deg1);
  sc_finalize<1, 32, false><<<4096, 256, 0, stream>>>(x, agg1, deg1, root1, b1, h, 32768);
  sc_pool<32><<<4096, 256, 0, stream>>>(h, cl1, pe1, 32768);

  // ---- level 2 ----
  sc_build_A<32><<<64, 1024, 0, stream>>>(pe1, ei2, ps2, bb2, 64, A, dsts, 65536);
  sc_cell_gemm<32, 64><<<dim3(64, 34), 256, 0, stream>>>(A, Wp2, base2, cnt2, dsts, agg2);
  sc_finalize<32, 64, true><<<2048, 256, 0, stream>>>(pe1, agg2, deg2, root2, b2, h, 8192);
  sc_pool<64><<<2048, 256, 0, stream>>>(h, cl2, pe2, 8192);

  // ---- level 3 ----
  sc_build_A<64><<<16, 1024, 0, stream>>>(pe2, ei3, ps3, bb3, 16, A, dsts, 16384);
  sc_cell_gemm<64, 128><<<dim3(64, 10), 256, 0, stream>>>(A, Wp3, base3, cnt3, dsts, agg3);
  sc_finalize<64, 128, true><<<1024, 256, 0, stream>>>(pe2, agg3, deg3, root3, b3, h, 2048);
  sc_pool<128><<<1024, 256, 0, stream>>>(h, cl3, pe3, 2048);

  // ---- level 4 ----
  sc_build_A<128><<<4, 1024, 0, stream>>>(pe3, ei4, ps4, bb4, 4, A, dsts, 4096);
  sc_cell_gemm<128, 256><<<dim3(64, 4), 256, 0, stream>>>(A, Wp4, base4, cnt4, dsts, agg4);
  sc_finalize<128, 256, true><<<512, 256, 0, stream>>>(pe3, agg4, deg4, root4, b4, h, 512);
  sc_pool<256><<<512, 256, 0, stream>>>(h, cl4, pe4, 512);

  // ---- FC head ----
  sc_fc1<<<dim3(2, 16), 256, 0, stream>>>(pe4, fc1w, fc1o);
  sc_fc2<<<8, 64, 0, stream>>>(fc1o, fc1b, fc2w, fc2b, out);
}

// Round 4
// 426.660 us; speedup vs baseline: 2.1446x; 1.3241x over previous
//
#include <hip/hip_runtime.h>

typedef __attribute__((ext_vector_type(8))) short bf16x8;
typedef __attribute__((ext_vector_type(4))) float f32x4;
typedef __attribute__((ext_vector_type(4))) unsigned short us4;
typedef __attribute__((ext_vector_type(8))) unsigned short us8;

#define DEVI __device__ __forceinline__

// work-table upper bounds: sum_c ceil(m_c/64) <= E/64 + 64, times K-slices
#define MAXW2 1088   // (65536/64 + 64) * 1
#define MAXW3 640    // (16384/64 + 64) * 2
#define MAXW4 512    // (4096/64  + 64) * 4

// ---------- helpers ----------

DEVI unsigned enc_pool(float f) {
  unsigned u = __float_as_uint(f);
  return (u & 0x80000000u) ? ~u : (u | 0x80000000u);
}
DEVI float dec_pool(unsigned k) {
  if (k == 0u) return 0.0f;  // empty voxel -> 0
  return __uint_as_float((k & 0x80000000u) ? (k ^ 0x80000000u) : ~k);
}
DEVI float eluf(float x) { return x > 0.0f ? x : expm1f(x); }
DEVI unsigned short to_bf16(float f) {  // round-to-nearest-even
  unsigned u = __float_as_uint(f);
  return (unsigned short)((u + 0x7FFFu + ((u >> 16) & 1u)) >> 16);
}

struct Basis { float bw[8]; int kidx[8]; int cell; };

DEVI Basis make_basis(const float* __restrict__ ps, int e) {
  Basis bs;
  float f[3]; int lo[3];
#pragma unroll
  for (int d = 0; d < 3; ++d) {
    float v = ps[e * 3 + d] * 4.0f;
    float fl = fminf(fmaxf(floorf(v), 0.0f), 3.0f);
    lo[d] = (int)fl;
    f[d] = v - fl;
  }
  bs.cell = lo[0] + 4 * lo[1] + 16 * lo[2];
#pragma unroll
  for (int s = 0; s < 8; ++s) {
    int b0 = s & 1, b1 = (s >> 1) & 1, b2 = (s >> 2) & 1;
    bs.bw[s] = (b0 ? f[0] : 1.0f - f[0]) * (b1 ? f[1] : 1.0f - f[1]) *
               (b2 ? f[2] : 1.0f - f[2]);
    bs.kidx[s] = (lo[0] + b0) + 5 * (lo[1] + b1) + 25 * (lo[2] + b2);
  }
  return bs;
}

// ---------- level 1: Cin=1 direct conv ----------
__global__ void sc_conv1(const float* __restrict__ x, const int* __restrict__ ei,
                         const float* __restrict__ ps, const float* __restrict__ W1,
                         float* __restrict__ agg, unsigned* __restrict__ deg) {
  int tid = blockIdx.x * blockDim.x + threadIdx.x;
  int e = tid >> 5, o = tid & 31;
  if (e >= 262144) return;
  int src = ei[e], dst = ei[262144 + e];
  Basis bs = make_basis(ps, e);
  float acc = 0.f;
#pragma unroll
  for (int s = 0; s < 8; ++s) acc += bs.bw[s] * W1[bs.kidx[s] * 32 + o];
  atomicAdd(agg + dst * 32 + o, x[src] * acc);
  if (o == 0) atomicAdd(deg + dst, 1u);
}

// ---------- fused finalize + pool: pe_out[cluster[n]] <- max(elu(agg/deg + x@root + b)) ----------
template <int CIN, int COUT, bool ENC>
__global__ void sc_finpool(const void* __restrict__ xv, const float* __restrict__ agg,
                           const unsigned* __restrict__ deg, const float* __restrict__ root,
                           const float* __restrict__ bias, const int* __restrict__ cluster,
                           unsigned* __restrict__ pe_out, int N) {
  int tid = blockIdx.x * blockDim.x + threadIdx.x;
  if (tid >= N * COUT) return;
  int n = tid / COUT, o = tid % COUT;
  unsigned dv = deg[n];
  float acc = agg[tid] / (float)(dv ? dv : 1u) + bias[o];
#pragma unroll 4
  for (int c = 0; c < CIN; ++c) {
    float xc = ENC ? dec_pool(((const unsigned*)xv)[n * CIN + c])
                   : ((const float*)xv)[n * CIN + c];
    acc += xc * root[c * COUT + o];
  }
  atomicMax(pe_out + (size_t)cluster[n] * COUT + o, enc_pool(eluf(acc)));
}

// ---------- counting: per-block 64-cell histogram, zero global atomics on cells ----------
__global__ __launch_bounds__(1024) void sc_count_all(
    const int* __restrict__ ei2, const float* __restrict__ ps2,
    const int* __restrict__ ei3, const float* __restrict__ ps3,
    const int* __restrict__ ei4, const float* __restrict__ ps4,
    unsigned* __restrict__ bc2, unsigned* __restrict__ bc3, unsigned* __restrict__ bc4,
    unsigned* __restrict__ deg2, unsigned* __restrict__ deg3, unsigned* __restrict__ deg4) {
  __shared__ unsigned hist[64];
  int b = blockIdx.x, t = threadIdx.x;
  const int* ei; const float* ps; unsigned *bc, *deg; int E, blk, NB;
  if (b < 64)      { ei = ei2; ps = ps2; bc = bc2; deg = deg2; E = 65536; blk = b;      NB = 64; }
  else if (b < 80) { ei = ei3; ps = ps3; bc = bc3; deg = deg3; E = 16384; blk = b - 64; NB = 16; }
  else             { ei = ei4; ps = ps4; bc = bc4; deg = deg4; E = 4096;  blk = b - 80; NB = 4;  }
  if (t < 64) hist[t] = 0;
  __syncthreads();
  int e = blk * 1024 + t;
  int cell = 0;
#pragma unroll
  for (int d = 0; d < 3; ++d) {
    float v = ps[e * 3 + d] * 4.0f;
    float fl = fminf(fmaxf(floorf(v), 0.0f), 3.0f);
    cell |= ((int)fl) << (2 * d);
  }
  atomicAdd(&hist[cell], 1u);
  atomicAdd(deg + ei[E + e], 1u);
  __syncthreads();
  if (t < 64) bc[(size_t)t * NB + blk] = hist[t];
}

// ---------- scan + dense work-table build ----------
// wave w handles level w+2: per-(cell,block) bases, per-cell counts/bases, and
// a dense GEMM work table: one entry per (cell, 64-row chunk, K-slice).
__global__ void sc_scan_all(const unsigned* __restrict__ bc2, const unsigned* __restrict__ bc3,
                            const unsigned* __restrict__ bc4,
                            unsigned* __restrict__ bb2, unsigned* __restrict__ bb3,
                            unsigned* __restrict__ bb4,
                            unsigned* __restrict__ cnt2, unsigned* __restrict__ cnt3,
                            unsigned* __restrict__ cnt4,
                            unsigned* __restrict__ base2, unsigned* __restrict__ base3,
                            unsigned* __restrict__ base4,
                            unsigned* __restrict__ wt2, unsigned* __restrict__ wt3,
                            unsigned* __restrict__ wt4) {
  int w = threadIdx.x >> 6, lane = threadIdx.x & 63;
  const unsigned* bc; unsigned *bb, *cnt, *bs, *wt; int NB, NKS, MAXW;
  if (w == 0)      { bc = bc2; bb = bb2; cnt = cnt2; bs = base2; wt = wt2; NB = 64; NKS = 1; MAXW = MAXW2; }
  else if (w == 1) { bc = bc3; bb = bb3; cnt = cnt3; bs = base3; wt = wt3; NB = 16; NKS = 2; MAXW = MAXW3; }
  else if (w == 2) { bc = bc4; bb = bb4; cnt = cnt4; bs = base4; wt = wt4; NB = 4;  NKS = 4; MAXW = MAXW4; }
  else return;
  unsigned run = 0, mycnt = 0;
  for (int c = 0; c < 64; ++c) {
    unsigned v = (lane < NB) ? bc[c * NB + lane] : 0u;
    int incl = (int)v;
#pragma unroll
    for (int d = 1; d < 64; d <<= 1) {
      int tv = __shfl_up(incl, d);
      if (lane >= d) incl += tv;
    }
    unsigned tot = (unsigned)__shfl(incl, NB - 1);
    if (lane < NB) bb[c * NB + lane] = run + (unsigned)incl - v;
    if (lane == c) mycnt = tot;
    if (lane == 0) { cnt[c] = tot; bs[c] = run; }
    run += tot;
  }
  // chunk counts per cell -> exclusive scan -> emit work entries
  int nch = (int)((mycnt + 63) >> 6);
  int cscan = nch;
#pragma unroll
  for (int d = 1; d < 64; d <<= 1) {
    int tv = __shfl_up(cscan, d);
    if (lane >= d) cscan += tv;
  }
  int cbase = cscan - nch;
  int CT = __shfl(cscan, 63);
  for (int ch = 0; ch < nch; ++ch)
    for (int ks = 0; ks < NKS; ++ks)
      wt[(cbase + ch) * NKS + ks] = ((unsigned)lane << 16) | ((unsigned)ch << 8) | (unsigned)ks;
  for (int i = CT * NKS + lane; i < MAXW; i += 64) wt[i] = 0xFFFFFFFFu;
}

// ---------- build A rows (cell-sorted), atomic-free positions ----------
template <int CIN>
__global__ __launch_bounds__(1024) void sc_build_A(
    const unsigned* __restrict__ xenc, const int* __restrict__ ei,
    const float* __restrict__ ps, const unsigned* __restrict__ blkbase, int NB,
    unsigned short* __restrict__ A, int* __restrict__ dsts, int E) {
  __shared__ unsigned hist[64];
  __shared__ int s_src[1024];
  __shared__ int s_pos[1024];
  __shared__ float s_bw[8][1025];
  int t = threadIdx.x, blk = blockIdx.x;
  if (t < 64) hist[t] = 0;
  __syncthreads();
  int e = blk * 1024 + t;
  int src = ei[e], dst = ei[E + e];
  Basis bs = make_basis(ps, e);
  unsigned r = atomicAdd(&hist[bs.cell], 1u);  // LDS rank within (block, cell)
  int pos = (int)(blkbase[bs.cell * NB + blk] + r);
  s_src[t] = src;
  s_pos[t] = pos;
#pragma unroll
  for (int s = 0; s < 8; ++s) s_bw[s][t] = bs.bw[s];
  dsts[pos] = dst;
  __syncthreads();
  int wv = t >> 6, lane = t & 63;
  int sB = lane >> 3;
  constexpr int K = 8 * CIN;
  for (int el = wv; el < 1024; el += 16) {
    int p = s_pos[el], sr = s_src[el];
    float b = s_bw[sB][el];
    if (CIN == 32) {
      uint4 xv = *(const uint4*)(xenc + (size_t)sr * 32 + (lane & 7) * 4);
      us4 o;
      o[0] = to_bf16(b * dec_pool(xv.x)); o[1] = to_bf16(b * dec_pool(xv.y));
      o[2] = to_bf16(b * dec_pool(xv.z)); o[3] = to_bf16(b * dec_pool(xv.w));
      *(us4*)(A + (size_t)p * K + lane * 4) = o;
    } else if (CIN == 64) {
      const uint4* xp = (const uint4*)(xenc + (size_t)sr * 64 + (lane & 7) * 8);
      uint4 xa = xp[0], xb = xp[1];
      us8 o;
      o[0] = to_bf16(b * dec_pool(xa.x)); o[1] = to_bf16(b * dec_pool(xa.y));
      o[2] = to_bf16(b * dec_pool(xa.z)); o[3] = to_bf16(b * dec_pool(xa.w));
      o[4] = to_bf16(b * dec_pool(xb.x)); o[5] = to_bf16(b * dec_pool(xb.y));
      o[6] = to_bf16(b * dec_pool(xb.z)); o[7] = to_bf16(b * dec_pool(xb.w));
      *(us8*)(A + (size_t)p * K + lane * 8) = o;
    } else {  // CIN == 128
      const uint4* xp = (const uint4*)(xenc + (size_t)sr * 128 + (lane & 7) * 16);
#pragma unroll
      for (int h = 0; h < 2; ++h) {
        uint4 xa = xp[h * 2], xb = xp[h * 2 + 1];
        us8 o;
        o[0] = to_bf16(b * dec_pool(xa.x)); o[1] = to_bf16(b * dec_pool(xa.y));
        o[2] = to_bf16(b * dec_pool(xa.z)); o[3] = to_bf16(b * dec_pool(xa.w));
        o[4] = to_bf16(b * dec_pool(xb.x)); o[5] = to_bf16(b * dec_pool(xb.y));
        o[6] = to_bf16(b * dec_pool(xb.z)); o[7] = to_bf16(b * dec_pool(xb.w));
        *(us8*)(A + (size_t)p * K + lane * 16 + h * 8) = o;
      }
    }
  }
}

// ---------- W -> bf16 fragment-ready permutation ----------
__global__ void sc_convert_W(const float* __restrict__ W2, const float* __restrict__ W3,
                             const float* __restrict__ W4, unsigned short* __restrict__ P2,
                             unsigned short* __restrict__ P3, unsigned short* __restrict__ P4) {
  int tid = blockIdx.x * blockDim.x + threadIdx.x;
  const int S2 = 125 * 32 * 64, S3 = 125 * 64 * 128, S4 = 125 * 128 * 256;
  const float* W; unsigned short* P; int CIN, COUT, idx;
  if (tid < S2)            { W = W2; P = P2; CIN = 32;  COUT = 64;  idx = tid; }
  else if (tid < S2 + S3)  { W = W3; P = P3; CIN = 64;  COUT = 128; idx = tid - S2; }
  else if (tid < S2 + S3 + S4) { W = W4; P = P4; CIN = 128; COUT = 256; idx = tid - S2 - S3; }
  else return;
  int mat = CIN * COUT;
  int k = idx / mat, off = idx % mat;
  int j = off & 7, g = (off >> 3) & 3;
  int rem = off >> 5;
  int n = rem % COUT, kb = rem / COUT;
  int c = kb * 32 + g * 8 + j;
  P[idx] = to_bf16(W[(k * CIN + c) * COUT + n]);
}

// ---------- GEMM: dense work table, B slice staged in LDS (80B padded rows) ----------
// entry: cell<<16 | chunk<<8 | kslice. Each block: 64 rows x COUT, K-slice of 256.
template <int CIN, int COUT>
DEVI void gemm_impl(const unsigned short* __restrict__ A, const unsigned short* __restrict__ Wp,
                    const unsigned* __restrict__ cnt, const unsigned* __restrict__ base,
                    const unsigned* __restrict__ wtab, const int* __restrict__ dsts,
                    float* __restrict__ agg) {
  constexpr int K = 8 * CIN;
  constexpr int NT = COUT / 16;
  constexpr int UPT = COUT / 32;           // staging 16B-units per thread per pass
  __shared__ __attribute__((aligned(16))) unsigned char lds[2 * COUT * 80];
  unsigned u = wtab[blockIdx.x];
  if (u == 0xFFFFFFFFu) return;
  int cell = u >> 16, chunk = (u >> 8) & 255, ks = u & 255;
  int m = (int)cnt[cell], cb = (int)base[cell];
  int row0 = chunk * 64;
  int tid = threadIdx.x;
  int wv = tid >> 6, lane = tid & 63, g4 = lane >> 4, ln = lane & 15;
  int lo0 = cell & 3, lo1 = (cell >> 2) & 3, lo2 = cell >> 4;
  int arow = cb + min(row0 + wv * 16 + ln, m - 1);
  f32x4 acc[NT];
#pragma unroll
  for (int t = 0; t < NT; ++t) acc[t] = (f32x4){0.f, 0.f, 0.f, 0.f};
#pragma unroll
  for (int pass = 0; pass < 4; ++pass) {
    int k0 = ks * 256 + pass * 64;
    __syncthreads();
#pragma unroll
    for (int i = 0; i < UPT; ++i) {
      int u16 = tid + i * 256;                 // 16B-unit id, [0, 8*COUT)
      int grp = u16 / (4 * COUT), win = u16 % (4 * COUT);
      int kg = k0 + grp * 32;
      int s = kg / CIN, kb = (kg % CIN) >> 5;
      int b0 = s & 1, b1 = (s >> 1) & 1, b2 = (s >> 2) & 1;
      int mat = (lo0 + b0) + 5 * (lo1 + b1) + 25 * (lo2 + b2);
      const us8* srcp = (const us8*)(Wp + (size_t)mat * (CIN * COUT) + (size_t)(kb * COUT * 4 + win) * 8);
      int r = grp * COUT + (win >> 2), gg = win & 3;
      *(us8*)(lds + r * 80 + gg * 16) = *srcp;
    }
    __syncthreads();
#pragma unroll
    for (int kk = 0; kk < 2; ++kk) {
      int kg = k0 + kk * 32;
      bf16x8 af = *(const bf16x8*)(A + (size_t)arow * K + kg + g4 * 8);
#pragma unroll
      for (int t = 0; t < NT; ++t) {
        int r = kk * COUT + t * 16 + ln;
        bf16x8 bfr = *(const bf16x8*)(lds + r * 80 + g4 * 16);
        acc[t] = __builtin_amdgcn_mfma_f32_16x16x32_bf16(af, bfr, acc[t], 0, 0, 0);
      }
    }
  }
  int row_b = row0 + wv * 16 + g4 * 4;
  int dstv[4];
#pragma unroll
  for (int r4 = 0; r4 < 4; ++r4)
    dstv[r4] = (row_b + r4 < m) ? dsts[cb + row_b + r4] : -1;
#pragma unroll
  for (int t = 0; t < NT; ++t) {
#pragma unroll
    for (int r4 = 0; r4 < 4; ++r4) {
      if (dstv[r4] >= 0)
        atomicAdd(agg + (size_t)dstv[r4] * COUT + t * 16 + ln, acc[t][r4]);
    }
  }
}

__global__ __launch_bounds__(256) void sc_gemm_l2(
    const unsigned short* A, const unsigned short* Wp, const unsigned* cnt,
    const unsigned* base, const unsigned* wtab, const int* dsts, float* agg) {
  gemm_impl<32, 64>(A, Wp, cnt, base, wtab, dsts, agg);
}
__global__ __launch_bounds__(256) void sc_gemm_l3(
    const unsigned short* A, const unsigned short* Wp, const unsigned* cnt,
    const unsigned* base, const unsigned* wtab, const int* dsts, float* agg) {
  gemm_impl<64, 128>(A, Wp, cnt, base, wtab, dsts, agg);
}
__global__ __launch_bounds__(256) void sc_gemm_l4(
    const unsigned short* A, const unsigned short* Wp, const unsigned* cnt,
    const unsigned* base, const unsigned* wtab, const int* dsts, float* agg) {
  gemm_impl<128, 256>(A, Wp, cnt, base, wtab, dsts, agg);
}

// ---------- FC head ----------
__global__ void sc_fc1(const unsigned* __restrict__ xenc, const float* __restrict__ w,
                       float* __restrict__ out) {
  int j = blockIdx.x * 256 + threadIdx.x;
  int c0 = blockIdx.y * 128;
  float acc[8];
#pragma unroll
  for (int b = 0; b < 8; ++b) acc[b] = 0.f;
  for (int c = c0; c < c0 + 128; ++c) {
    float wv = w[c * 512 + j];
#pragma unroll
    for (int b = 0; b < 8; ++b) acc[b] += dec_pool(xenc[b * 2048 + c]) * wv;
  }
#pragma unroll
  for (int b = 0; b < 8; ++b) atomicAdd(out + b * 512 + j, acc[b]);
}

__global__ void sc_fc2(const float* __restrict__ h, const float* __restrict__ b1,
                       const float* __restrict__ w2, const float* __restrict__ b2,
                       float* __restrict__ out) {
  int b = blockIdx.x;
  int lane = threadIdx.x;
  float part[10];
#pragma unroll
  for (int o = 0; o < 10; ++o) part[o] = 0.f;
  for (int k = 0; k < 8; ++k) {
    int c = k * 64 + lane;
    float v = eluf(h[b * 512 + c] + b1[c]);
#pragma unroll
    for (int o = 0; o < 10; ++o) part[o] += v * w2[c * 10 + o];
  }
#pragma unroll
  for (int o = 0; o < 10; ++o) {
#pragma unroll
    for (int d = 32; d > 0; d >>= 1) part[o] += __shfl_down(part[o], d);
  }
  if (lane == 0) {
    float z[10], mx = -1e30f;
#pragma unroll
    for (int o = 0; o < 10; ++o) { z[o] = part[o] + b2[o]; mx = fmaxf(mx, z[o]); }
    float sum = 0.f;
#pragma unroll
    for (int o = 0; o < 10; ++o) sum += expf(z[o] - mx);
    float lse = mx + logf(sum);
#pragma unroll
    for (int o = 0; o < 10; ++o) out[b * 10 + o] = z[o] - lse;
  }
}

// ---------- host ----------
extern "C" void kernel_launch(void* const* d_in, const int* in_sizes, int n_in,
                              void* d_out, int out_size, void* d_ws, size_t ws_size,
                              hipStream_t stream) {
  (void)in_sizes; (void)n_in; (void)out_size; (void)ws_size;
  const float* x    = (const float*)d_in[0];
  const int*   ei1  = (const int*)d_in[1];
  const float* ps1  = (const float*)d_in[2];
  const int*   cl1  = (const int*)d_in[3];
  const int*   ei2  = (const int*)d_in[4];
  const float* ps2  = (const float*)d_in[5];
  const int*   cl2  = (const int*)d_in[6];
  const int*   ei3  = (const int*)d_in[7];
  const float* ps3  = (const float*)d_in[8];
  const int*   cl3  = (const int*)d_in[9];
  const int*   ei4  = (const int*)d_in[10];
  const float* ps4  = (const float*)d_in[11];
  const int*   cl4  = (const int*)d_in[12];
  const float* W1   = (const float*)d_in[13];
  const float* root1= (const float*)d_in[14];
  const float* b1   = (const float*)d_in[15];
  const float* W2   = (const float*)d_in[16];
  const float* root2= (const float*)d_in[17];
  const float* b2   = (const float*)d_in[18];
  const float* W3   = (const float*)d_in[19];
  const float* root3= (const float*)d_in[20];
  const float* b3   = (const float*)d_in[21];
  const float* W4   = (const float*)d_in[22];
  const float* root4= (const float*)d_in[23];
  const float* b4   = (const float*)d_in[24];
  const float* fc1w = (const float*)d_in[25];
  const float* fc1b = (const float*)d_in[26];
  const float* fc2w = (const float*)d_in[27];
  const float* fc2b = (const float*)d_in[28];
  float* out = (float*)d_out;

  char* ws = (char*)d_ws;
  size_t off = 0;
  auto alloc = [&](size_t bytes) -> void* {
    void* p = ws + off;
    off = (off + bytes + 255) & ~(size_t)255;
    return p;
  };
  // ---- zero-init region (one memset) ----
  float*    agg1 = (float*)alloc(32768ull * 32 * 4);
  float*    agg2 = (float*)alloc(8192ull * 64 * 4);
  float*    agg3 = (float*)alloc(2048ull * 128 * 4);
  float*    agg4 = (float*)alloc(512ull * 256 * 4);
  unsigned* deg1 = (unsigned*)alloc(32768ull * 4);
  unsigned* deg2 = (unsigned*)alloc(8192ull * 4);
  unsigned* deg3 = (unsigned*)alloc(2048ull * 4);
  unsigned* deg4 = (unsigned*)alloc(512ull * 4);
  unsigned* pe1  = (unsigned*)alloc(8192ull * 32 * 4);
  unsigned* pe2  = (unsigned*)alloc(2048ull * 64 * 4);
  unsigned* pe3  = (unsigned*)alloc(512ull * 128 * 4);
  unsigned* pe4  = (unsigned*)alloc(64ull * 256 * 4);
  float*    fc1o = (float*)alloc(8ull * 512 * 4);
  size_t zero_bytes = off;
  // ---- non-zero region (fully written each call) ----
  unsigned* bc2   = (unsigned*)alloc(64ull * 64 * 4);
  unsigned* bc3   = (unsigned*)alloc(64ull * 16 * 4);
  unsigned* bc4   = (unsigned*)alloc(64ull * 4 * 4);
  unsigned* bb2   = (unsigned*)alloc(64ull * 64 * 4);
  unsigned* bb3   = (unsigned*)alloc(64ull * 16 * 4);
  unsigned* bb4   = (unsigned*)alloc(64ull * 4 * 4);
  unsigned* cnt2  = (unsigned*)alloc(64 * 4);
  unsigned* cnt3  = (unsigned*)alloc(64 * 4);
  unsigned* cnt4  = (unsigned*)alloc(64 * 4);
  unsigned* base2 = (unsigned*)alloc(64 * 4);
  unsigned* base3 = (unsigned*)alloc(64 * 4);
  unsigned* base4 = (unsigned*)alloc(64 * 4);
  unsigned* wt2   = (unsigned*)alloc(MAXW2 * 4);
  unsigned* wt3   = (unsigned*)alloc(MAXW3 * 4);
  unsigned* wt4   = (unsigned*)alloc(MAXW4 * 4);
  unsigned short* Wp2 = (unsigned short*)alloc(125ull * 32 * 64 * 2);
  unsigned short* Wp3 = (unsigned short*)alloc(125ull * 64 * 128 * 2);
  unsigned short* Wp4 = (unsigned short*)alloc(125ull * 128 * 256 * 2);
  unsigned short* A   = (unsigned short*)alloc(65536ull * 256 * 2);  // reused L2..L4
  int*            dsts = (int*)alloc(65536ull * 4);                  // reused

  hipMemsetAsync(d_ws, 0, zero_bytes, stream);
  sc_convert_W<<<21000, 256, 0, stream>>>(W2, W3, W4, Wp2, Wp3, Wp4);
  sc_count_all<<<84, 1024, 0, stream>>>(ei2, ps2, ei3, ps3, ei4, ps4,
                                        bc2, bc3, bc4, deg2, deg3, deg4);
  sc_scan_all<<<1, 256, 0, stream>>>(bc2, bc3, bc4, bb2, bb3, bb4,
                                     cnt2, cnt3, cnt4, base2, base3, base4,
                                     wt2, wt3, wt4);

  // ---- level 1 ----
  sc_conv1<<<32768, 256, 0, stream>>>(x, ei1, ps1, W1, agg1, deg1);
  sc_finpool<1, 32, false><<<4096, 256, 0, stream>>>(x, agg1, deg1, root1, b1, cl1, pe1, 32768);

  // ---- level 2 ----
  sc_build_A<32><<<64, 1024, 0, stream>>>(pe1, ei2, ps2, bb2, 64, A, dsts, 65536);
  sc_gemm_l2<<<MAXW2, 256, 0, stream>>>(A, Wp2, cnt2, base2, wt2, dsts, agg2);
  sc_finpool<32, 64, true><<<2048, 256, 0, stream>>>(pe1, agg2, deg2, root2, b2, cl2, pe2, 8192);

  // ---- level 3 ----
  sc_build_A<64><<<16, 1024, 0, stream>>>(pe2, ei3, ps3, bb3, 16, A, dsts, 16384);
  sc_gemm_l3<<<MAXW3, 256, 0, stream>>>(A, Wp3, cnt3, base3, wt3, dsts, agg3);
  sc_finpool<64, 128, true><<<1024, 256, 0, stream>>>(pe2, agg3, deg3, root3, b3, cl3, pe3, 2048);

  // ---- level 4 ----
  sc_build_A<128><<<4, 1024, 0, stream>>>(pe3, ei4, ps4, bb4, 4, A, dsts, 4096);
  sc_gemm_l4<<<MAXW4, 256, 0, stream>>>(A, Wp4, cnt4, base4, wt4, dsts, agg4);
  sc_finpool<128, 256, true><<<512, 256, 0, stream>>>(pe3, agg4, deg4, root4, b4, cl4, pe4, 512);

  // ---- FC head ----
  sc_fc1<<<dim3(2, 16), 256, 0, stream>>>(pe4, fc1w, fc1o);
  sc_fc2<<<8, 64, 0, stream>>>(fc1o, fc1b, fc2w, fc2b, out);
}

// Round 5
// 285.681 us; speedup vs baseline: 3.2029x; 1.4935x over previous
//
#include <hip/hip_runtime.h>

typedef __attribute__((ext_vector_type(8))) short bf16x8;
typedef __attribute__((ext_vector_type(4))) float f32x4;
typedef __attribute__((ext_vector_type(4))) unsigned short us4;
typedef __attribute__((ext_vector_type(8))) unsigned short us8;

#define DEVI __device__ __forceinline__

// work-table upper bounds: sum_c ceil(m_c/64) <= E/64 + 64, times K-slices
#define MAXW2 1088   // (65536/64 + 64) * 1
#define MAXW3 640    // (16384/64 + 64) * 2
#define MAXW4 512    // (4096/64  + 64) * 4

// ---------- helpers ----------

DEVI unsigned enc_pool(float f) {
  unsigned u = __float_as_uint(f);
  return (u & 0x80000000u) ? ~u : (u | 0x80000000u);
}
DEVI float dec_pool(unsigned k) {
  if (k == 0u) return 0.0f;  // empty voxel -> 0
  return __uint_as_float((k & 0x80000000u) ? (k ^ 0x80000000u) : ~k);
}
DEVI float eluf(float x) { return x > 0.0f ? x : expm1f(x); }
DEVI unsigned short to_bf16(float f) {  // round-to-nearest-even
  unsigned u = __float_as_uint(f);
  return (unsigned short)((u + 0x7FFFu + ((u >> 16) & 1u)) >> 16);
}

struct Basis { float bw[8]; int kidx[8]; int cell; };

DEVI Basis make_basis(const float* __restrict__ ps, int e) {
  Basis bs;
  float f[3]; int lo[3];
#pragma unroll
  for (int d = 0; d < 3; ++d) {
    float v = ps[e * 3 + d] * 4.0f;
    float fl = fminf(fmaxf(floorf(v), 0.0f), 3.0f);
    lo[d] = (int)fl;
    f[d] = v - fl;
  }
  bs.cell = lo[0] + 4 * lo[1] + 16 * lo[2];
#pragma unroll
  for (int s = 0; s < 8; ++s) {
    int b0 = s & 1, b1 = (s >> 1) & 1, b2 = (s >> 2) & 1;
    bs.bw[s] = (b0 ? f[0] : 1.0f - f[0]) * (b1 ? f[1] : 1.0f - f[1]) *
               (b2 ? f[2] : 1.0f - f[2]);
    bs.kidx[s] = (lo[0] + b0) + 5 * (lo[1] + b1) + 25 * (lo[2] + b2);
  }
  return bs;
}

DEVI int cell_of(const float* __restrict__ ps, int e) {
  int cell = 0;
#pragma unroll
  for (int d = 0; d < 3; ++d) {
    float v = ps[e * 3 + d] * 4.0f;
    float fl = fminf(fmaxf(floorf(v), 0.0f), 3.0f);
    cell |= ((int)fl) << (2 * d);
  }
  return cell;
}

// ---------- level 1: Cin=1 direct conv ----------
__global__ void sc_conv1(const float* __restrict__ x, const int* __restrict__ ei,
                         const float* __restrict__ ps, const float* __restrict__ W1,
                         float* __restrict__ agg, unsigned* __restrict__ deg) {
  int tid = blockIdx.x * blockDim.x + threadIdx.x;
  int e = tid >> 5, o = tid & 31;
  if (e >= 262144) return;
  int src = ei[e], dst = ei[262144 + e];
  Basis bs = make_basis(ps, e);
  float acc = 0.f;
#pragma unroll
  for (int s = 0; s < 8; ++s) acc += bs.bw[s] * W1[bs.kidx[s] * 32 + o];
  atomicAdd(agg + dst * 32 + o, x[src] * acc);
  if (o == 0) atomicAdd(deg + dst, 1u);
}

// ---------- fused finalize + pool ----------
template <int CIN, int COUT, bool ENC>
__global__ void sc_finpool(const void* __restrict__ xv, const float* __restrict__ agg,
                           const unsigned* __restrict__ deg, const float* __restrict__ root,
                           const float* __restrict__ bias, const int* __restrict__ cluster,
                           unsigned* __restrict__ pe_out, int N) {
  int tid = blockIdx.x * blockDim.x + threadIdx.x;
  if (tid >= N * COUT) return;
  int n = tid / COUT, o = tid % COUT;
  unsigned dv = deg[n];
  float acc = agg[tid] / (float)(dv ? dv : 1u) + bias[o];
#pragma unroll 4
  for (int c = 0; c < CIN; ++c) {
    float xc = ENC ? dec_pool(((const unsigned*)xv)[n * CIN + c])
                   : ((const float*)xv)[n * CIN + c];
    acc += xc * root[c * COUT + o];
  }
  atomicMax(pe_out + (size_t)cluster[n] * COUT + o, enc_pool(eluf(acc)));
}

// ---------- counting: per-block 64-cell histogram ----------
__global__ __launch_bounds__(1024) void sc_count_all(
    const int* __restrict__ ei2, const float* __restrict__ ps2,
    const int* __restrict__ ei3, const float* __restrict__ ps3,
    const int* __restrict__ ei4, const float* __restrict__ ps4,
    unsigned* __restrict__ bc2, unsigned* __restrict__ bc3, unsigned* __restrict__ bc4,
    unsigned* __restrict__ deg2, unsigned* __restrict__ deg3, unsigned* __restrict__ deg4) {
  __shared__ unsigned hist[64];
  int b = blockIdx.x, t = threadIdx.x;
  const int* ei; const float* ps; unsigned *bc, *deg; int E, blk, NB;
  if (b < 64)      { ei = ei2; ps = ps2; bc = bc2; deg = deg2; E = 65536; blk = b;      NB = 64; }
  else if (b < 80) { ei = ei3; ps = ps3; bc = bc3; deg = deg3; E = 16384; blk = b - 64; NB = 16; }
  else             { ei = ei4; ps = ps4; bc = bc4; deg = deg4; E = 4096;  blk = b - 80; NB = 4;  }
  if (t < 64) hist[t] = 0;
  __syncthreads();
  int e = blk * 1024 + t;
  atomicAdd(&hist[cell_of(ps, e)], 1u);
  atomicAdd(deg + ei[E + e], 1u);
  __syncthreads();
  if (t < 64) bc[(size_t)t * NB + blk] = hist[t];
}

// ---------- scan + dense work-table build ----------
__global__ void sc_scan_all(const unsigned* __restrict__ bc2, const unsigned* __restrict__ bc3,
                            const unsigned* __restrict__ bc4,
                            unsigned* __restrict__ bb2, unsigned* __restrict__ bb3,
                            unsigned* __restrict__ bb4,
                            unsigned* __restrict__ cnt2, unsigned* __restrict__ cnt3,
                            unsigned* __restrict__ cnt4,
                            unsigned* __restrict__ base2, unsigned* __restrict__ base3,
                            unsigned* __restrict__ base4,
                            unsigned* __restrict__ wt2, unsigned* __restrict__ wt3,
                            unsigned* __restrict__ wt4) {
  int w = threadIdx.x >> 6, lane = threadIdx.x & 63;
  const unsigned* bc; unsigned *bb, *cnt, *bs, *wt; int NB, NKS, MAXW;
  if (w == 0)      { bc = bc2; bb = bb2; cnt = cnt2; bs = base2; wt = wt2; NB = 64; NKS = 1; MAXW = MAXW2; }
  else if (w == 1) { bc = bc3; bb = bb3; cnt = cnt3; bs = base3; wt = wt3; NB = 16; NKS = 2; MAXW = MAXW3; }
  else if (w == 2) { bc = bc4; bb = bb4; cnt = cnt4; bs = base4; wt = wt4; NB = 4;  NKS = 4; MAXW = MAXW4; }
  else return;
  unsigned run = 0, mycnt = 0;
  for (int c = 0; c < 64; ++c) {
    unsigned v = (lane < NB) ? bc[c * NB + lane] : 0u;
    int incl = (int)v;
#pragma unroll
    for (int d = 1; d < 64; d <<= 1) {
      int tv = __shfl_up(incl, d);
      if (lane >= d) incl += tv;
    }
    unsigned tot = (unsigned)__shfl(incl, NB - 1);
    if (lane < NB) bb[c * NB + lane] = run + (unsigned)incl - v;
    if (lane == c) mycnt = tot;
    if (lane == 0) { cnt[c] = tot; bs[c] = run; }
    run += tot;
  }
  int nch = (int)((mycnt + 63) >> 6);
  int cscan = nch;
#pragma unroll
  for (int d = 1; d < 64; d <<= 1) {
    int tv = __shfl_up(cscan, d);
    if (lane >= d) cscan += tv;
  }
  int cbase = cscan - nch;
  int CT = __shfl(cscan, 63);
  for (int ch = 0; ch < nch; ++ch)
    for (int ks = 0; ks < NKS; ++ks)
      wt[(cbase + ch) * NKS + ks] = ((unsigned)lane << 16) | ((unsigned)ch << 8) | (unsigned)ks;
  for (int i = CT * NKS + lane; i < MAXW; i += 64) wt[i] = 0xFFFFFFFFu;
}

// ---------- rank: pos[e] for every edge of every level, dsts[pos]=dst ----------
__global__ __launch_bounds__(1024) void sc_rank_all(
    const int* __restrict__ ei2, const float* __restrict__ ps2,
    const int* __restrict__ ei3, const float* __restrict__ ps3,
    const int* __restrict__ ei4, const float* __restrict__ ps4,
    const unsigned* __restrict__ bb2, const unsigned* __restrict__ bb3,
    const unsigned* __restrict__ bb4,
    int* __restrict__ pos2, int* __restrict__ pos3, int* __restrict__ pos4,
    int* __restrict__ dst2, int* __restrict__ dst3, int* __restrict__ dst4) {
  __shared__ unsigned hist[64];
  int b = blockIdx.x, t = threadIdx.x;
  const int* ei; const float* ps; const unsigned* bb; int *pos, *dsts; int E, blk, NB;
  if (b < 64)      { ei = ei2; ps = ps2; bb = bb2; pos = pos2; dsts = dst2; E = 65536; blk = b;      NB = 64; }
  else if (b < 80) { ei = ei3; ps = ps3; bb = bb3; pos = pos3; dsts = dst3; E = 16384; blk = b - 64; NB = 16; }
  else             { ei = ei4; ps = ps4; bb = bb4; pos = pos4; dsts = dst4; E = 4096;  blk = b - 80; NB = 4;  }
  if (t < 64) hist[t] = 0;
  __syncthreads();
  int e = blk * 1024 + t;
  int cell = cell_of(ps, e);
  unsigned r = atomicAdd(&hist[cell], 1u);
  int p = (int)(bb[cell * NB + blk] + r);
  pos[e] = p;
  dsts[p] = ei[E + e];
}

// ---------- fill A rows: one wave per edge, full-device grid ----------
// A[pos[e]][s*CIN+c] = bw[s] * x[src][c]; lane handles s=lane>>3, c-slice (lane&7).
template <int CIN>
__global__ void sc_fill(const unsigned* __restrict__ xenc, const int* __restrict__ ei,
                        const float* __restrict__ ps, const int* __restrict__ posb,
                        unsigned short* __restrict__ A, int E) {
  int gid = blockIdx.x * blockDim.x + threadIdx.x;
  int e = gid >> 6, lane = gid & 63;
  if (e >= E) return;
  int src = ei[e];
  int p = posb[e];
  float f[3];
#pragma unroll
  for (int d = 0; d < 3; ++d) {
    float v = ps[e * 3 + d] * 4.0f;
    float fl = fminf(fmaxf(floorf(v), 0.0f), 3.0f);
    f[d] = v - fl;
  }
  int sB = lane >> 3;
  int b0 = sB & 1, b1 = (sB >> 1) & 1, b2 = sB >> 2;
  float b = (b0 ? f[0] : 1.0f - f[0]) * (b1 ? f[1] : 1.0f - f[1]) *
            (b2 ? f[2] : 1.0f - f[2]);
  constexpr int K = 8 * CIN;
  if (CIN == 32) {
    uint4 xv = *(const uint4*)(xenc + (size_t)src * 32 + (lane & 7) * 4);
    us4 o;
    o[0] = to_bf16(b * dec_pool(xv.x)); o[1] = to_bf16(b * dec_pool(xv.y));
    o[2] = to_bf16(b * dec_pool(xv.z)); o[3] = to_bf16(b * dec_pool(xv.w));
    *(us4*)(A + (size_t)p * K + lane * 4) = o;
  } else if (CIN == 64) {
    const uint4* xp = (const uint4*)(xenc + (size_t)src * 64 + (lane & 7) * 8);
    uint4 xa = xp[0], xb = xp[1];
    us8 o;
    o[0] = to_bf16(b * dec_pool(xa.x)); o[1] = to_bf16(b * dec_pool(xa.y));
    o[2] = to_bf16(b * dec_pool(xa.z)); o[3] = to_bf16(b * dec_pool(xa.w));
    o[4] = to_bf16(b * dec_pool(xb.x)); o[5] = to_bf16(b * dec_pool(xb.y));
    o[6] = to_bf16(b * dec_pool(xb.z)); o[7] = to_bf16(b * dec_pool(xb.w));
    *(us8*)(A + (size_t)p * K + lane * 8) = o;
  } else {  // CIN == 128
    const uint4* xp = (const uint4*)(xenc + (size_t)src * 128 + (lane & 7) * 16);
#pragma unroll
    for (int h = 0; h < 2; ++h) {
      uint4 xa = xp[h * 2], xb = xp[h * 2 + 1];
      us8 o;
      o[0] = to_bf16(b * dec_pool(xa.x)); o[1] = to_bf16(b * dec_pool(xa.y));
      o[2] = to_bf16(b * dec_pool(xa.z)); o[3] = to_bf16(b * dec_pool(xa.w));
      o[4] = to_bf16(b * dec_pool(xb.x)); o[5] = to_bf16(b * dec_pool(xb.y));
      o[6] = to_bf16(b * dec_pool(xb.z)); o[7] = to_bf16(b * dec_pool(xb.w));
      *(us8*)(A + (size_t)p * K + lane * 16 + h * 8) = o;
    }
  }
}

// ---------- W -> bf16 fragment-ready permutation ----------
__global__ void sc_convert_W(const float* __restrict__ W2, const float* __restrict__ W3,
                             const float* __restrict__ W4, unsigned short* __restrict__ P2,
                             unsigned short* __restrict__ P3, unsigned short* __restrict__ P4) {
  int tid = blockIdx.x * blockDim.x + threadIdx.x;
  const int S2 = 125 * 32 * 64, S3 = 125 * 64 * 128, S4 = 125 * 128 * 256;
  const float* W; unsigned short* P; int CIN, COUT, idx;
  if (tid < S2)            { W = W2; P = P2; CIN = 32;  COUT = 64;  idx = tid; }
  else if (tid < S2 + S3)  { W = W3; P = P3; CIN = 64;  COUT = 128; idx = tid - S2; }
  else if (tid < S2 + S3 + S4) { W = W4; P = P4; CIN = 128; COUT = 256; idx = tid - S2 - S3; }
  else return;
  int mat = CIN * COUT;
  int k = idx / mat, off = idx % mat;
  int j = off & 7, g = (off >> 3) & 3;
  int rem = off >> 5;
  int n = rem % COUT, kb = rem / COUT;
  int c = kb * 32 + g * 8 + j;
  P[idx] = to_bf16(W[(k * CIN + c) * COUT + n]);
}

// ---------- GEMM: dense work table, B slice staged in LDS (80B padded rows) ----------
template <int CIN, int COUT>
DEVI void gemm_impl(const unsigned short* __restrict__ A, const unsigned short* __restrict__ Wp,
                    const unsigned* __restrict__ cnt, const unsigned* __restrict__ base,
                    const unsigned* __restrict__ wtab, const int* __restrict__ dsts,
                    float* __restrict__ agg) {
  constexpr int K = 8 * CIN;
  constexpr int NT = COUT / 16;
  constexpr int UPT = COUT / 32;
  __shared__ __attribute__((aligned(16))) unsigned char lds[2 * COUT * 80];
  unsigned u = wtab[blockIdx.x];
  if (u == 0xFFFFFFFFu) return;
  int cell = u >> 16, chunk = (u >> 8) & 255, ks = u & 255;
  int m = (int)cnt[cell], cb = (int)base[cell];
  int row0 = chunk * 64;
  int tid = threadIdx.x;
  int wv = tid >> 6, lane = tid & 63, g4 = lane >> 4, ln = lane & 15;
  int lo0 = cell & 3, lo1 = (cell >> 2) & 3, lo2 = cell >> 4;
  int arow = cb + min(row0 + wv * 16 + ln, m - 1);
  f32x4 acc[NT];
#pragma unroll
  for (int t = 0; t < NT; ++t) acc[t] = (f32x4){0.f, 0.f, 0.f, 0.f};
#pragma unroll
  for (int pass = 0; pass < 4; ++pass) {
    int k0 = ks * 256 + pass * 64;
    __syncthreads();
#pragma unroll
    for (int i = 0; i < UPT; ++i) {
      int u16 = tid + i * 256;
      int grp = u16 / (4 * COUT), win = u16 % (4 * COUT);
      int kg = k0 + grp * 32;
      int s = kg / CIN, kb = (kg % CIN) >> 5;
      int b0 = s & 1, b1 = (s >> 1) & 1, b2 = (s >> 2) & 1;
      int mat = (lo0 + b0) + 5 * (lo1 + b1) + 25 * (lo2 + b2);
      const us8* srcp = (const us8*)(Wp + (size_t)mat * (CIN * COUT) + (size_t)(kb * COUT * 4 + win) * 8);
      int r = grp * COUT + (win >> 2), gg = win & 3;
      *(us8*)(lds + r * 80 + gg * 16) = *srcp;
    }
    __syncthreads();
#pragma unroll
    for (int kk = 0; kk < 2; ++kk) {
      int kg = k0 + kk * 32;
      bf16x8 af = *(const bf16x8*)(A + (size_t)arow * K + kg + g4 * 8);
#pragma unroll
      for (int t = 0; t < NT; ++t) {
        int r = kk * COUT + t * 16 + ln;
        bf16x8 bfr = *(const bf16x8*)(lds + r * 80 + g4 * 16);
        acc[t] = __builtin_amdgcn_mfma_f32_16x16x32_bf16(af, bfr, acc[t], 0, 0, 0);
      }
    }
  }
  int row_b = row0 + wv * 16 + g4 * 4;
  int dstv[4];
#pragma unroll
  for (int r4 = 0; r4 < 4; ++r4)
    dstv[r4] = (row_b + r4 < m) ? dsts[cb + row_b + r4] : -1;
#pragma unroll
  for (int t = 0; t < NT; ++t) {
#pragma unroll
    for (int r4 = 0; r4 < 4; ++r4) {
      if (dstv[r4] >= 0)
        atomicAdd(agg + (size_t)dstv[r4] * COUT + t * 16 + ln, acc[t][r4]);
    }
  }
}

__global__ __launch_bounds__(256) void sc_gemm_l2(
    const unsigned short* A, const unsigned short* Wp, const unsigned* cnt,
    const unsigned* base, const unsigned* wtab, const int* dsts, float* agg) {
  gemm_impl<32, 64>(A, Wp, cnt, base, wtab, dsts, agg);
}
__global__ __launch_bounds__(256) void sc_gemm_l3(
    const unsigned short* A, const unsigned short* Wp, const unsigned* cnt,
    const unsigned* base, const unsigned* wtab, const int* dsts, float* agg) {
  gemm_impl<64, 128>(A, Wp, cnt, base, wtab, dsts, agg);
}
__global__ __launch_bounds__(256) void sc_gemm_l4(
    const unsigned short* A, const unsigned short* Wp, const unsigned* cnt,
    const unsigned* base, const unsigned* wtab, const int* dsts, float* agg) {
  gemm_impl<128, 256>(A, Wp, cnt, base, wtab, dsts, agg);
}

// ---------- FC head ----------
__global__ void sc_fc1(const unsigned* __restrict__ xenc, const float* __restrict__ w,
                       float* __restrict__ out) {
  int j = blockIdx.x * 256 + threadIdx.x;
  int c0 = blockIdx.y * 128;
  float acc[8];
#pragma unroll
  for (int b = 0; b < 8; ++b) acc[b] = 0.f;
  for (int c = c0; c < c0 + 128; ++c) {
    float wv = w[c * 512 + j];
#pragma unroll
    for (int b = 0; b < 8; ++b) acc[b] += dec_pool(xenc[b * 2048 + c]) * wv;
  }
#pragma unroll
  for (int b = 0; b < 8; ++b) atomicAdd(out + b * 512 + j, acc[b]);
}

__global__ void sc_fc2(const float* __restrict__ h, const float* __restrict__ b1,
                       const float* __restrict__ w2, const float* __restrict__ b2,
                       float* __restrict__ out) {
  int b = blockIdx.x;
  int lane = threadIdx.x;
  float part[10];
#pragma unroll
  for (int o = 0; o < 10; ++o) part[o] = 0.f;
  for (int k = 0; k < 8; ++k) {
    int c = k * 64 + lane;
    float v = eluf(h[b * 512 + c] + b1[c]);
#pragma unroll
    for (int o = 0; o < 10; ++o) part[o] += v * w2[c * 10 + o];
  }
#pragma unroll
  for (int o = 0; o < 10; ++o) {
#pragma unroll
    for (int d = 32; d > 0; d >>= 1) part[o] += __shfl_down(part[o], d);
  }
  if (lane == 0) {
    float z[10], mx = -1e30f;
#pragma unroll
    for (int o = 0; o < 10; ++o) { z[o] = part[o] + b2[o]; mx = fmaxf(mx, z[o]); }
    float sum = 0.f;
#pragma unroll
    for (int o = 0; o < 10; ++o) sum += expf(z[o] - mx);
    float lse = mx + logf(sum);
#pragma unroll
    for (int o = 0; o < 10; ++o) out[b * 10 + o] = z[o] - lse;
  }
}

// ---------- host ----------
extern "C" void kernel_launch(void* const* d_in, const int* in_sizes, int n_in,
                              void* d_out, int out_size, void* d_ws, size_t ws_size,
                              hipStream_t stream) {
  (void)in_sizes; (void)n_in; (void)out_size; (void)ws_size;
  const float* x    = (const float*)d_in[0];
  const int*   ei1  = (const int*)d_in[1];
  const float* ps1  = (const float*)d_in[2];
  const int*   cl1  = (const int*)d_in[3];
  const int*   ei2  = (const int*)d_in[4];
  const float* ps2  = (const float*)d_in[5];
  const int*   cl2  = (const int*)d_in[6];
  const int*   ei3  = (const int*)d_in[7];
  const float* ps3  = (const float*)d_in[8];
  const int*   cl3  = (const int*)d_in[9];
  const int*   ei4  = (const int*)d_in[10];
  const float* ps4  = (const float*)d_in[11];
  const int*   cl4  = (const int*)d_in[12];
  const float* W1   = (const float*)d_in[13];
  const float* root1= (const float*)d_in[14];
  const float* b1   = (const float*)d_in[15];
  const float* W2   = (const float*)d_in[16];
  const float* root2= (const float*)d_in[17];
  const float* b2   = (const float*)d_in[18];
  const float* W3   = (const float*)d_in[19];
  const float* root3= (const float*)d_in[20];
  const float* b3   = (const float*)d_in[21];
  const float* W4   = (const float*)d_in[22];
  const float* root4= (const float*)d_in[23];
  const float* b4   = (const float*)d_in[24];
  const float* fc1w = (const float*)d_in[25];
  const float* fc1b = (const float*)d_in[26];
  const float* fc2w = (const float*)d_in[27];
  const float* fc2b = (const float*)d_in[28];
  float* out = (float*)d_out;

  char* ws = (char*)d_ws;
  size_t off = 0;
  auto alloc = [&](size_t bytes) -> void* {
    void* p = ws + off;
    off = (off + bytes + 255) & ~(size_t)255;
    return p;
  };
  // ---- zero-init region (one memset) ----
  float*    agg1 = (float*)alloc(32768ull * 32 * 4);
  float*    agg2 = (float*)alloc(8192ull * 64 * 4);
  float*    agg3 = (float*)alloc(2048ull * 128 * 4);
  float*    agg4 = (float*)alloc(512ull * 256 * 4);
  unsigned* deg1 = (unsigned*)alloc(32768ull * 4);
  unsigned* deg2 = (unsigned*)alloc(8192ull * 4);
  unsigned* deg3 = (unsigned*)alloc(2048ull * 4);
  unsigned* deg4 = (unsigned*)alloc(512ull * 4);
  unsigned* pe1  = (unsigned*)alloc(8192ull * 32 * 4);
  unsigned* pe2  = (unsigned*)alloc(2048ull * 64 * 4);
  unsigned* pe3  = (unsigned*)alloc(512ull * 128 * 4);
  unsigned* pe4  = (unsigned*)alloc(64ull * 256 * 4);
  float*    fc1o = (float*)alloc(8ull * 512 * 4);
  size_t zero_bytes = off;
  // ---- non-zero region (fully written each call) ----
  unsigned* bc2   = (unsigned*)alloc(64ull * 64 * 4);
  unsigned* bc3   = (unsigned*)alloc(64ull * 16 * 4);
  unsigned* bc4   = (unsigned*)alloc(64ull * 4 * 4);
  unsigned* bb2   = (unsigned*)alloc(64ull * 64 * 4);
  unsigned* bb3   = (unsigned*)alloc(64ull * 16 * 4);
  unsigned* bb4   = (unsigned*)alloc(64ull * 4 * 4);
  unsigned* cnt2  = (unsigned*)alloc(64 * 4);
  unsigned* cnt3  = (unsigned*)alloc(64 * 4);
  unsigned* cnt4  = (unsigned*)alloc(64 * 4);
  unsigned* base2 = (unsigned*)alloc(64 * 4);
  unsigned* base3 = (unsigned*)alloc(64 * 4);
  unsigned* base4 = (unsigned*)alloc(64 * 4);
  unsigned* wt2   = (unsigned*)alloc(MAXW2 * 4);
  unsigned* wt3   = (unsigned*)alloc(MAXW3 * 4);
  unsigned* wt4   = (unsigned*)alloc(MAXW4 * 4);
  int* pos2 = (int*)alloc(65536ull * 4);
  int* pos3 = (int*)alloc(16384ull * 4);
  int* pos4 = (int*)alloc(4096ull * 4);
  int* dst2 = (int*)alloc(65536ull * 4);
  int* dst3 = (int*)alloc(16384ull * 4);
  int* dst4 = (int*)alloc(4096ull * 4);
  unsigned short* Wp2 = (unsigned short*)alloc(125ull * 32 * 64 * 2);
  unsigned short* Wp3 = (unsigned short*)alloc(125ull * 64 * 128 * 2);
  unsigned short* Wp4 = (unsigned short*)alloc(125ull * 128 * 256 * 2);
  unsigned short* A   = (unsigned short*)alloc(65536ull * 256 * 2);  // reused L2..L4

  hipMemsetAsync(d_ws, 0, zero_bytes, stream);
  sc_convert_W<<<21000, 256, 0, stream>>>(W2, W3, W4, Wp2, Wp3, Wp4);
  sc_count_all<<<84, 1024, 0, stream>>>(ei2, ps2, ei3, ps3, ei4, ps4,
                                        bc2, bc3, bc4, deg2, deg3, deg4);
  sc_scan_all<<<1, 256, 0, stream>>>(bc2, bc3, bc4, bb2, bb3, bb4,
                                     cnt2, cnt3, cnt4, base2, base3, base4,
                                     wt2, wt3, wt4);
  sc_rank_all<<<84, 1024, 0, stream>>>(ei2, ps2, ei3, ps3, ei4, ps4,
                                       bb2, bb3, bb4, pos2, pos3, pos4,
                                       dst2, dst3, dst4);

  // ---- level 1 ----
  sc_conv1<<<32768, 256, 0, stream>>>(x, ei1, ps1, W1, agg1, deg1);
  sc_finpool<1, 32, false><<<4096, 256, 0, stream>>>(x, agg1, deg1, root1, b1, cl1, pe1, 32768);

  // ---- level 2 ----
  sc_fill<32><<<16384, 256, 0, stream>>>(pe1, ei2, ps2, pos2, A, 65536);
  sc_gemm_l2<<<MAXW2, 256, 0, stream>>>(A, Wp2, cnt2, base2, wt2, dst2, agg2);
  sc_finpool<32, 64, true><<<2048, 256, 0, stream>>>(pe1, agg2, deg2, root2, b2, cl2, pe2, 8192);

  // ---- level 3 ----
  sc_fill<64><<<4096, 256, 0, stream>>>(pe2, ei3, ps3, pos3, A, 16384);
  sc_gemm_l3<<<MAXW3, 256, 0, stream>>>(A, Wp3, cnt3, base3, wt3, dst3, agg3);
  sc_finpool<64, 128, true><<<1024, 256, 0, stream>>>(pe2, agg3, deg3, root3, b3, cl3, pe3, 2048);

  // ---- level 4 ----
  sc_fill<128><<<1024, 256, 0, stream>>>(pe3, ei4, ps4, pos4, A, 4096);
  sc_gemm_l4<<<MAXW4, 256, 0, stream>>>(A, Wp4, cnt4, base4, wt4, dst4, agg4);
  sc_finpool<128, 256, true><<<512, 256, 0, stream>>>(pe3, agg4, deg4, root4, b4, cl4, pe4, 512);

  // ---- FC head ----
  sc_fc1<<<dim3(2, 16), 256, 0, stream>>>(pe4, fc1w, fc1o);
  sc_fc2<<<8, 64, 0, stream>>>(fc1o, fc1b, fc2w, fc2b, out);
}

// Round 6
// 255.044 us; speedup vs baseline: 3.5877x; 1.1201x over previous
//
#include <hip/hip_runtime.h>

typedef __attribute__((ext_vector_type(8))) short bf16x8;
typedef __attribute__((ext_vector_type(4))) float f32x4;
typedef __attribute__((ext_vector_type(4))) unsigned short us4;
typedef __attribute__((ext_vector_type(8))) unsigned short us8;

#define DEVI __device__ __forceinline__

// work-table upper bounds: sum_c ceil(m_c/64) <= E/64 + 64, times K-slices
#define MAXW2 1088   // (65536/64 + 64) * 1
#define MAXW3 640    // (16384/64 + 64) * 2
#define MAXW4 512    // (4096/64  + 64) * 4

// ---------- helpers ----------

DEVI unsigned enc_pool(float f) {
  unsigned u = __float_as_uint(f);
  return (u & 0x80000000u) ? ~u : (u | 0x80000000u);
}
DEVI float dec_pool(unsigned k) {
  if (k == 0u) return 0.0f;  // empty voxel -> 0
  return __uint_as_float((k & 0x80000000u) ? (k ^ 0x80000000u) : ~k);
}
DEVI float eluf(float x) { return x > 0.0f ? x : expm1f(x); }
DEVI unsigned short to_bf16(float f) {  // round-to-nearest-even
  unsigned u = __float_as_uint(f);
  return (unsigned short)((u + 0x7FFFu + ((u >> 16) & 1u)) >> 16);
}

struct Basis { float bw[8]; int kidx[8]; int cell; };

DEVI Basis make_basis(const float* __restrict__ ps, int e) {
  Basis bs;
  float f[3]; int lo[3];
#pragma unroll
  for (int d = 0; d < 3; ++d) {
    float v = ps[e * 3 + d] * 4.0f;
    float fl = fminf(fmaxf(floorf(v), 0.0f), 3.0f);
    lo[d] = (int)fl;
    f[d] = v - fl;
  }
  bs.cell = lo[0] + 4 * lo[1] + 16 * lo[2];
#pragma unroll
  for (int s = 0; s < 8; ++s) {
    int b0 = s & 1, b1 = (s >> 1) & 1, b2 = (s >> 2) & 1;
    bs.bw[s] = (b0 ? f[0] : 1.0f - f[0]) * (b1 ? f[1] : 1.0f - f[1]) *
               (b2 ? f[2] : 1.0f - f[2]);
    bs.kidx[s] = (lo[0] + b0) + 5 * (lo[1] + b1) + 25 * (lo[2] + b2);
  }
  return bs;
}

DEVI int cell_of(const float* __restrict__ ps, int e) {
  int cell = 0;
#pragma unroll
  for (int d = 0; d < 3; ++d) {
    float v = ps[e * 3 + d] * 4.0f;
    float fl = fminf(fmaxf(floorf(v), 0.0f), 3.0f);
    cell |= ((int)fl) << (2 * d);
  }
  return cell;
}

// ---------- level 1: Cin=1 direct conv ----------
__global__ void sc_conv1(const float* __restrict__ x, const int* __restrict__ ei,
                         const float* __restrict__ ps, const float* __restrict__ W1,
                         float* __restrict__ agg, unsigned* __restrict__ deg) {
  int tid = blockIdx.x * blockDim.x + threadIdx.x;
  int e = tid >> 5, o = tid & 31;
  if (e >= 262144) return;
  int src = ei[e], dst = ei[262144 + e];
  Basis bs = make_basis(ps, e);
  float acc = 0.f;
#pragma unroll
  for (int s = 0; s < 8; ++s) acc += bs.bw[s] * W1[bs.kidx[s] * 32 + o];
  atomicAdd(agg + dst * 32 + o, x[src] * acc);
  if (o == 0) atomicAdd(deg + dst, 1u);
}

// ---------- fused finalize + pool ----------
template <int CIN, int COUT, bool ENC>
__global__ void sc_finpool(const void* __restrict__ xv, const float* __restrict__ agg,
                           const unsigned* __restrict__ deg, const float* __restrict__ root,
                           const float* __restrict__ bias, const int* __restrict__ cluster,
                           unsigned* __restrict__ pe_out, int N) {
  int tid = blockIdx.x * blockDim.x + threadIdx.x;
  if (tid >= N * COUT) return;
  int n = tid / COUT, o = tid % COUT;
  unsigned dv = deg[n];
  float acc = agg[tid] / (float)(dv ? dv : 1u) + bias[o];
#pragma unroll 4
  for (int c = 0; c < CIN; ++c) {
    float xc = ENC ? dec_pool(((const unsigned*)xv)[n * CIN + c])
                   : ((const float*)xv)[n * CIN + c];
    acc += xc * root[c * COUT + o];
  }
  atomicMax(pe_out + (size_t)cluster[n] * COUT + o, enc_pool(eluf(acc)));
}

// ---------- counting: per-block 64-cell histogram ----------
__global__ __launch_bounds__(1024) void sc_count_all(
    const int* __restrict__ ei2, const float* __restrict__ ps2,
    const int* __restrict__ ei3, const float* __restrict__ ps3,
    const int* __restrict__ ei4, const float* __restrict__ ps4,
    unsigned* __restrict__ bc2, unsigned* __restrict__ bc3, unsigned* __restrict__ bc4,
    unsigned* __restrict__ deg2, unsigned* __restrict__ deg3, unsigned* __restrict__ deg4) {
  __shared__ unsigned hist[64];
  int b = blockIdx.x, t = threadIdx.x;
  const int* ei; const float* ps; unsigned *bc, *deg; int E, blk, NB;
  if (b < 64)      { ei = ei2; ps = ps2; bc = bc2; deg = deg2; E = 65536; blk = b;      NB = 64; }
  else if (b < 80) { ei = ei3; ps = ps3; bc = bc3; deg = deg3; E = 16384; blk = b - 64; NB = 16; }
  else             { ei = ei4; ps = ps4; bc = bc4; deg = deg4; E = 4096;  blk = b - 80; NB = 4;  }
  if (t < 64) hist[t] = 0;
  __syncthreads();
  int e = blk * 1024 + t;
  atomicAdd(&hist[cell_of(ps, e)], 1u);
  atomicAdd(deg + ei[E + e], 1u);
  __syncthreads();
  if (t < 64) bc[(size_t)t * NB + blk] = hist[t];
}

// ---------- scan + dense work-table build ----------
__global__ void sc_scan_all(const unsigned* __restrict__ bc2, const unsigned* __restrict__ bc3,
                            const unsigned* __restrict__ bc4,
                            unsigned* __restrict__ bb2, unsigned* __restrict__ bb3,
                            unsigned* __restrict__ bb4,
                            unsigned* __restrict__ cnt2, unsigned* __restrict__ cnt3,
                            unsigned* __restrict__ cnt4,
                            unsigned* __restrict__ base2, unsigned* __restrict__ base3,
                            unsigned* __restrict__ base4,
                            unsigned* __restrict__ wt2, unsigned* __restrict__ wt3,
                            unsigned* __restrict__ wt4) {
  int w = threadIdx.x >> 6, lane = threadIdx.x & 63;
  const unsigned* bc; unsigned *bb, *cnt, *bs, *wt; int NB, NKS, MAXW;
  if (w == 0)      { bc = bc2; bb = bb2; cnt = cnt2; bs = base2; wt = wt2; NB = 64; NKS = 1; MAXW = MAXW2; }
  else if (w == 1) { bc = bc3; bb = bb3; cnt = cnt3; bs = base3; wt = wt3; NB = 16; NKS = 2; MAXW = MAXW3; }
  else if (w == 2) { bc = bc4; bb = bb4; cnt = cnt4; bs = base4; wt = wt4; NB = 4;  NKS = 4; MAXW = MAXW4; }
  else return;
  unsigned run = 0, mycnt = 0;
  for (int c = 0; c < 64; ++c) {
    unsigned v = (lane < NB) ? bc[c * NB + lane] : 0u;
    int incl = (int)v;
#pragma unroll
    for (int d = 1; d < 64; d <<= 1) {
      int tv = __shfl_up(incl, d);
      if (lane >= d) incl += tv;
    }
    unsigned tot = (unsigned)__shfl(incl, NB - 1);
    if (lane < NB) bb[c * NB + lane] = run + (unsigned)incl - v;
    if (lane == c) mycnt = tot;
    if (lane == 0) { cnt[c] = tot; bs[c] = run; }
    run += tot;
  }
  int nch = (int)((mycnt + 63) >> 6);
  int cscan = nch;
#pragma unroll
  for (int d = 1; d < 64; d <<= 1) {
    int tv = __shfl_up(cscan, d);
    if (lane >= d) cscan += tv;
  }
  int cbase = cscan - nch;
  int CT = __shfl(cscan, 63);
  for (int ch = 0; ch < nch; ++ch)
    for (int ks = 0; ks < NKS; ++ks)
      wt[(cbase + ch) * NKS + ks] = ((unsigned)lane << 16) | ((unsigned)ch << 8) | (unsigned)ks;
  for (int i = CT * NKS + lane; i < MAXW; i += 64) wt[i] = 0xFFFFFFFFu;
}

// ---------- rank: pos[e] for every edge of every level, dsts[pos]=dst ----------
__global__ __launch_bounds__(1024) void sc_rank_all(
    const int* __restrict__ ei2, const float* __restrict__ ps2,
    const int* __restrict__ ei3, const float* __restrict__ ps3,
    const int* __restrict__ ei4, const float* __restrict__ ps4,
    const unsigned* __restrict__ bb2, const unsigned* __restrict__ bb3,
    const unsigned* __restrict__ bb4,
    int* __restrict__ pos2, int* __restrict__ pos3, int* __restrict__ pos4,
    int* __restrict__ dst2, int* __restrict__ dst3, int* __restrict__ dst4) {
  __shared__ unsigned hist[64];
  int b = blockIdx.x, t = threadIdx.x;
  const int* ei; const float* ps; const unsigned* bb; int *pos, *dsts; int E, blk, NB;
  if (b < 64)      { ei = ei2; ps = ps2; bb = bb2; pos = pos2; dsts = dst2; E = 65536; blk = b;      NB = 64; }
  else if (b < 80) { ei = ei3; ps = ps3; bb = bb3; pos = pos3; dsts = dst3; E = 16384; blk = b - 64; NB = 16; }
  else             { ei = ei4; ps = ps4; bb = bb4; pos = pos4; dsts = dst4; E = 4096;  blk = b - 80; NB = 4;  }
  if (t < 64) hist[t] = 0;
  __syncthreads();
  int e = blk * 1024 + t;
  int cell = cell_of(ps, e);
  unsigned r = atomicAdd(&hist[cell], 1u);
  int p = (int)(bb[cell * NB + blk] + r);
  pos[e] = p;
  dsts[p] = ei[E + e];
}

// ---------- fill A rows: one wave per edge, full-device grid ----------
template <int CIN>
__global__ void sc_fill(const unsigned* __restrict__ xenc, const int* __restrict__ ei,
                        const float* __restrict__ ps, const int* __restrict__ posb,
                        unsigned short* __restrict__ A, int E) {
  int gid = blockIdx.x * blockDim.x + threadIdx.x;
  int e = gid >> 6, lane = gid & 63;
  if (e >= E) return;
  int src = ei[e];
  int p = posb[e];
  float f[3];
#pragma unroll
  for (int d = 0; d < 3; ++d) {
    float v = ps[e * 3 + d] * 4.0f;
    float fl = fminf(fmaxf(floorf(v), 0.0f), 3.0f);
    f[d] = v - fl;
  }
  int sB = lane >> 3;
  int b0 = sB & 1, b1 = (sB >> 1) & 1, b2 = sB >> 2;
  float b = (b0 ? f[0] : 1.0f - f[0]) * (b1 ? f[1] : 1.0f - f[1]) *
            (b2 ? f[2] : 1.0f - f[2]);
  constexpr int K = 8 * CIN;
  if (CIN == 32) {
    uint4 xv = *(const uint4*)(xenc + (size_t)src * 32 + (lane & 7) * 4);
    us4 o;
    o[0] = to_bf16(b * dec_pool(xv.x)); o[1] = to_bf16(b * dec_pool(xv.y));
    o[2] = to_bf16(b * dec_pool(xv.z)); o[3] = to_bf16(b * dec_pool(xv.w));
    *(us4*)(A + (size_t)p * K + lane * 4) = o;
  } else if (CIN == 64) {
    const uint4* xp = (const uint4*)(xenc + (size_t)src * 64 + (lane & 7) * 8);
    uint4 xa = xp[0], xb = xp[1];
    us8 o;
    o[0] = to_bf16(b * dec_pool(xa.x)); o[1] = to_bf16(b * dec_pool(xa.y));
    o[2] = to_bf16(b * dec_pool(xa.z)); o[3] = to_bf16(b * dec_pool(xa.w));
    o[4] = to_bf16(b * dec_pool(xb.x)); o[5] = to_bf16(b * dec_pool(xb.y));
    o[6] = to_bf16(b * dec_pool(xb.z)); o[7] = to_bf16(b * dec_pool(xb.w));
    *(us8*)(A + (size_t)p * K + lane * 8) = o;
  } else {  // CIN == 128
    const uint4* xp = (const uint4*)(xenc + (size_t)src * 128 + (lane & 7) * 16);
#pragma unroll
    for (int h = 0; h < 2; ++h) {
      uint4 xa = xp[h * 2], xb = xp[h * 2 + 1];
      us8 o;
      o[0] = to_bf16(b * dec_pool(xa.x)); o[1] = to_bf16(b * dec_pool(xa.y));
      o[2] = to_bf16(b * dec_pool(xa.z)); o[3] = to_bf16(b * dec_pool(xa.w));
      o[4] = to_bf16(b * dec_pool(xb.x)); o[5] = to_bf16(b * dec_pool(xb.y));
      o[6] = to_bf16(b * dec_pool(xb.z)); o[7] = to_bf16(b * dec_pool(xb.w));
      *(us8*)(A + (size_t)p * K + lane * 16 + h * 8) = o;
    }
  }
}

// ---------- W -> bf16 fragment-ready permutation ----------
__global__ void sc_convert_W(const float* __restrict__ W2, const float* __restrict__ W3,
                             const float* __restrict__ W4, unsigned short* __restrict__ P2,
                             unsigned short* __restrict__ P3, unsigned short* __restrict__ P4) {
  int tid = blockIdx.x * blockDim.x + threadIdx.x;
  const int S2 = 125 * 32 * 64, S3 = 125 * 64 * 128, S4 = 125 * 128 * 256;
  const float* W; unsigned short* P; int CIN, COUT, idx;
  if (tid < S2)            { W = W2; P = P2; CIN = 32;  COUT = 64;  idx = tid; }
  else if (tid < S2 + S3)  { W = W3; P = P3; CIN = 64;  COUT = 128; idx = tid - S2; }
  else if (tid < S2 + S3 + S4) { W = W4; P = P4; CIN = 128; COUT = 256; idx = tid - S2 - S3; }
  else return;
  int mat = CIN * COUT;
  int k = idx / mat, off = idx % mat;
  int j = off & 7, g = (off >> 3) & 3;
  int rem = off >> 5;
  int n = rem % COUT, kb = rem / COUT;
  int c = kb * 32 + g * 8 + j;
  P[idx] = to_bf16(W[(k * CIN + c) * COUT + n]);
}

// ---------- GEMM: dense work table, B slice staged in LDS (80B padded rows) ----------
template <int CIN, int COUT>
DEVI void gemm_impl(const unsigned short* __restrict__ A, const unsigned short* __restrict__ Wp,
                    const unsigned* __restrict__ cnt, const unsigned* __restrict__ base,
                    const unsigned* __restrict__ wtab, const int* __restrict__ dsts,
                    float* __restrict__ agg) {
  constexpr int K = 8 * CIN;
  constexpr int NT = COUT / 16;
  constexpr int UPT = COUT / 32;
  __shared__ __attribute__((aligned(16))) unsigned char lds[2 * COUT * 80];
  unsigned u = wtab[blockIdx.x];
  if (u == 0xFFFFFFFFu) return;
  int cell = u >> 16, chunk = (u >> 8) & 255, ks = u & 255;
  int m = (int)cnt[cell], cb = (int)base[cell];
  int row0 = chunk * 64;
  int tid = threadIdx.x;
  int wv = tid >> 6, lane = tid & 63, g4 = lane >> 4, ln = lane & 15;
  int lo0 = cell & 3, lo1 = (cell >> 2) & 3, lo2 = cell >> 4;
  int arow = cb + min(row0 + wv * 16 + ln, m - 1);
  f32x4 acc[NT];
#pragma unroll
  for (int t = 0; t < NT; ++t) acc[t] = (f32x4){0.f, 0.f, 0.f, 0.f};
#pragma unroll
  for (int pass = 0; pass < 4; ++pass) {
    int k0 = ks * 256 + pass * 64;
    __syncthreads();
#pragma unroll
    for (int i = 0; i < UPT; ++i) {
      int u16 = tid + i * 256;
      int grp = u16 / (4 * COUT), win = u16 % (4 * COUT);
      int kg = k0 + grp * 32;
      int s = kg / CIN, kb = (kg % CIN) >> 5;
      int b0 = s & 1, b1 = (s >> 1) & 1, b2 = (s >> 2) & 1;
      int mat = (lo0 + b0) + 5 * (lo1 + b1) + 25 * (lo2 + b2);
      const us8* srcp = (const us8*)(Wp + (size_t)mat * (CIN * COUT) + (size_t)(kb * COUT * 4 + win) * 8);
      int r = grp * COUT + (win >> 2), gg = win & 3;
      *(us8*)(lds + r * 80 + gg * 16) = *srcp;
    }
    __syncthreads();
#pragma unroll
    for (int kk = 0; kk < 2; ++kk) {
      int kg = k0 + kk * 32;
      bf16x8 af = *(const bf16x8*)(A + (size_t)arow * K + kg + g4 * 8);
#pragma unroll
      for (int t = 0; t < NT; ++t) {
        int r = kk * COUT + t * 16 + ln;
        bf16x8 bfr = *(const bf16x8*)(lds + r * 80 + g4 * 16);
        acc[t] = __builtin_amdgcn_mfma_f32_16x16x32_bf16(af, bfr, acc[t], 0, 0, 0);
      }
    }
  }
  int row_b = row0 + wv * 16 + g4 * 4;
  int dstv[4];
#pragma unroll
  for (int r4 = 0; r4 < 4; ++r4)
    dstv[r4] = (row_b + r4 < m) ? dsts[cb + row_b + r4] : -1;
#pragma unroll
  for (int t = 0; t < NT; ++t) {
#pragma unroll
    for (int r4 = 0; r4 < 4; ++r4) {
      if (dstv[r4] >= 0)
        atomicAdd(agg + (size_t)dstv[r4] * COUT + t * 16 + ln, acc[t][r4]);
    }
  }
}

__global__ __launch_bounds__(256) void sc_gemm_l2(
    const unsigned short* A, const unsigned short* Wp, const unsigned* cnt,
    const unsigned* base, const unsigned* wtab, const int* dsts, float* agg) {
  gemm_impl<32, 64>(A, Wp, cnt, base, wtab, dsts, agg);
}
__global__ __launch_bounds__(256) void sc_gemm_l3(
    const unsigned short* A, const unsigned short* Wp, const unsigned* cnt,
    const unsigned* base, const unsigned* wtab, const int* dsts, float* agg) {
  gemm_impl<64, 128>(A, Wp, cnt, base, wtab, dsts, agg);
}
__global__ __launch_bounds__(256) void sc_gemm_l4(
    const unsigned short* A, const unsigned short* Wp, const unsigned* cnt,
    const unsigned* base, const unsigned* wtab, const int* dsts, float* agg) {
  gemm_impl<128, 256>(A, Wp, cnt, base, wtab, dsts, agg);
}

// ---------- FC head ----------
// grid: dim3(2 j-tiles, 64 c-chunks of 32). Coalesced w reads, LDS-staged x.
__global__ void sc_fc1(const unsigned* __restrict__ xenc, const float* __restrict__ w,
                       float* __restrict__ out) {
  __shared__ float sx[8][32];
  int t = threadIdx.x;
  int j = blockIdx.x * 256 + t;          // 0..511
  int c0 = blockIdx.y * 32;              // 64 chunks
  if (t < 256) {
    int b = t >> 5, c = t & 31;
    sx[b][c] = dec_pool(xenc[b * 2048 + c0 + c]);
  }
  __syncthreads();
  float acc[8];
#pragma unroll
  for (int b = 0; b < 8; ++b) acc[b] = 0.f;
#pragma unroll 4
  for (int cc = 0; cc < 32; ++cc) {
    float wv = w[(size_t)(c0 + cc) * 512 + j];
#pragma unroll
    for (int b = 0; b < 8; ++b) acc[b] += sx[b][cc] * wv;
  }
#pragma unroll
  for (int b = 0; b < 8; ++b) atomicAdd(out + b * 512 + j, acc[b]);
}

__global__ void sc_fc2(const float* __restrict__ h, const float* __restrict__ b1,
                       const float* __restrict__ w2, const float* __restrict__ b2,
                       float* __restrict__ out) {
  int b = blockIdx.x;
  int lane = threadIdx.x;
  float part[10];
#pragma unroll
  for (int o = 0; o < 10; ++o) part[o] = 0.f;
  for (int k = 0; k < 8; ++k) {
    int c = k * 64 + lane;
    float v = eluf(h[b * 512 + c] + b1[c]);
#pragma unroll
    for (int o = 0; o < 10; ++o) part[o] += v * w2[c * 10 + o];
  }
#pragma unroll
  for (int o = 0; o < 10; ++o) {
#pragma unroll
    for (int d = 32; d > 0; d >>= 1) part[o] += __shfl_down(part[o], d);
  }
  if (lane == 0) {
    float z[10], mx = -1e30f;
#pragma unroll
    for (int o = 0; o < 10; ++o) { z[o] = part[o] + b2[o]; mx = fmaxf(mx, z[o]); }
    float sum = 0.f;
#pragma unroll
    for (int o = 0; o < 10; ++o) sum += expf(z[o] - mx);
    float lse = mx + logf(sum);
#pragma unroll
    for (int o = 0; o < 10; ++o) out[b * 10 + o] = z[o] - lse;
  }
}

// ---------- host ----------
extern "C" void kernel_launch(void* const* d_in, const int* in_sizes, int n_in,
                              void* d_out, int out_size, void* d_ws, size_t ws_size,
                              hipStream_t stream) {
  (void)in_sizes; (void)n_in; (void)out_size; (void)ws_size;
  const float* x    = (const float*)d_in[0];
  const int*   ei1  = (const int*)d_in[1];
  const float* ps1  = (const float*)d_in[2];
  const int*   cl1  = (const int*)d_in[3];
  const int*   ei2  = (const int*)d_in[4];
  const float* ps2  = (const float*)d_in[5];
  const int*   cl2  = (const int*)d_in[6];
  const int*   ei3  = (const int*)d_in[7];
  const float* ps3  = (const float*)d_in[8];
  const int*   cl3  = (const int*)d_in[9];
  const int*   ei4  = (const int*)d_in[10];
  const float* ps4  = (const float*)d_in[11];
  const int*   cl4  = (const int*)d_in[12];
  const float* W1   = (const float*)d_in[13];
  const float* root1= (const float*)d_in[14];
  const float* b1   = (const float*)d_in[15];
  const float* W2   = (const float*)d_in[16];
  const float* root2= (const float*)d_in[17];
  const float* b2   = (const float*)d_in[18];
  const float* W3   = (const float*)d_in[19];
  const float* root3= (const float*)d_in[20];
  const float* b3   = (const float*)d_in[21];
  const float* W4   = (const float*)d_in[22];
  const float* root4= (const float*)d_in[23];
  const float* b4   = (const float*)d_in[24];
  const float* fc1w = (const float*)d_in[25];
  const float* fc1b = (const float*)d_in[26];
  const float* fc2w = (const float*)d_in[27];
  const float* fc2b = (const float*)d_in[28];
  float* out = (float*)d_out;

  char* ws = (char*)d_ws;
  size_t off = 0;
  auto alloc = [&](size_t bytes) -> void* {
    void* p = ws + off;
    off = (off + bytes + 255) & ~(size_t)255;
    return p;
  };
  // ---- zero-init region (one memset) ----
  float*    agg1 = (float*)alloc(32768ull * 32 * 4);
  float*    agg2 = (float*)alloc(8192ull * 64 * 4);
  float*    agg3 = (float*)alloc(2048ull * 128 * 4);
  float*    agg4 = (float*)alloc(512ull * 256 * 4);
  unsigned* deg1 = (unsigned*)alloc(32768ull * 4);
  unsigned* deg2 = (unsigned*)alloc(8192ull * 4);
  unsigned* deg3 = (unsigned*)alloc(2048ull * 4);
  unsigned* deg4 = (unsigned*)alloc(512ull * 4);
  unsigned* pe1  = (unsigned*)alloc(8192ull * 32 * 4);
  unsigned* pe2  = (unsigned*)alloc(2048ull * 64 * 4);
  unsigned* pe3  = (unsigned*)alloc(512ull * 128 * 4);
  unsigned* pe4  = (unsigned*)alloc(64ull * 256 * 4);
  float*    fc1o = (float*)alloc(8ull * 512 * 4);
  size_t zero_bytes = off;
  // ---- non-zero region (fully written each call) ----
  unsigned* bc2   = (unsigned*)alloc(64ull * 64 * 4);
  unsigned* bc3   = (unsigned*)alloc(64ull * 16 * 4);
  unsigned* bc4   = (unsigned*)alloc(64ull * 4 * 4);
  unsigned* bb2   = (unsigned*)alloc(64ull * 64 * 4);
  unsigned* bb3   = (unsigned*)alloc(64ull * 16 * 4);
  unsigned* bb4   = (unsigned*)alloc(64ull * 4 * 4);
  unsigned* cnt2  = (unsigned*)alloc(64 * 4);
  unsigned* cnt3  = (unsigned*)alloc(64 * 4);
  unsigned* cnt4  = (unsigned*)alloc(64 * 4);
  unsigned* base2 = (unsigned*)alloc(64 * 4);
  unsigned* base3 = (unsigned*)alloc(64 * 4);
  unsigned* base4 = (unsigned*)alloc(64 * 4);
  unsigned* wt2   = (unsigned*)alloc(MAXW2 * 4);
  unsigned* wt3   = (unsigned*)alloc(MAXW3 * 4);
  unsigned* wt4   = (unsigned*)alloc(MAXW4 * 4);
  int* pos2 = (int*)alloc(65536ull * 4);
  int* pos3 = (int*)alloc(16384ull * 4);
  int* pos4 = (int*)alloc(4096ull * 4);
  int* dst2 = (int*)alloc(65536ull * 4);
  int* dst3 = (int*)alloc(16384ull * 4);
  int* dst4 = (int*)alloc(4096ull * 4);
  unsigned short* Wp2 = (unsigned short*)alloc(125ull * 32 * 64 * 2);
  unsigned short* Wp3 = (unsigned short*)alloc(125ull * 64 * 128 * 2);
  unsigned short* Wp4 = (unsigned short*)alloc(125ull * 128 * 256 * 2);
  unsigned short* A   = (unsigned short*)alloc(65536ull * 256 * 2);  // reused L2..L4

  hipMemsetAsync(d_ws, 0, zero_bytes, stream);
  sc_convert_W<<<21000, 256, 0, stream>>>(W2, W3, W4, Wp2, Wp3, Wp4);
  sc_count_all<<<84, 1024, 0, stream>>>(ei2, ps2, ei3, ps3, ei4, ps4,
                                        bc2, bc3, bc4, deg2, deg3, deg4);
  sc_scan_all<<<1, 256, 0, stream>>>(bc2, bc3, bc4, bb2, bb3, bb4,
                                     cnt2, cnt3, cnt4, base2, base3, base4,
                                     wt2, wt3, wt4);
  sc_rank_all<<<84, 1024, 0, stream>>>(ei2, ps2, ei3, ps3, ei4, ps4,
                                       bb2, bb3, bb4, pos2, pos3, pos4,
                                       dst2, dst3, dst4);

  // ---- level 1 ----
  sc_conv1<<<32768, 256, 0, stream>>>(x, ei1, ps1, W1, agg1, deg1);
  sc_finpool<1, 32, false><<<4096, 256, 0, stream>>>(x, agg1, deg1, root1, b1, cl1, pe1, 32768);

  // ---- level 2 ----
  sc_fill<32><<<16384, 256, 0, stream>>>(pe1, ei2, ps2, pos2, A, 65536);
  sc_gemm_l2<<<MAXW2, 256, 0, stream>>>(A, Wp2, cnt2, base2, wt2, dst2, agg2);
  sc_finpool<32, 64, true><<<2048, 256, 0, stream>>>(pe1, agg2, deg2, root2, b2, cl2, pe2, 8192);

  // ---- level 3 ----
  sc_fill<64><<<4096, 256, 0, stream>>>(pe2, ei3, ps3, pos3, A, 16384);
  sc_gemm_l3<<<MAXW3, 256, 0, stream>>>(A, Wp3, cnt3, base3, wt3, dst3, agg3);
  sc_finpool<64, 128, true><<<1024, 256, 0, stream>>>(pe2, agg3, deg3, root3, b3, cl3, pe3, 2048);

  // ---- level 4 ----
  sc_fill<128><<<1024, 256, 0, stream>>>(pe3, ei4, ps4, pos4, A, 4096);
  sc_gemm_l4<<<MAXW4, 256, 0, stream>>>(A, Wp4, cnt4, base4, wt4, dst4, agg4);
  sc_finpool<128, 256, true><<<512, 256, 0, stream>>>(pe3, agg4, deg4, root4, b4, cl4, pe4, 512);

  // ---- FC head ----
  sc_fc1<<<dim3(2, 64), 256, 0, stream>>>(pe4, fc1w, fc1o);
  sc_fc2<<<8, 64, 0, stream>>>(fc1o, fc1b, fc2w, fc2b, out);
}